// Round 7
// baseline (419.020 us; speedup 1.0000x reference)
//
#include <hip/hip_runtime.h>

#define N_TOK 8192
#define D_IN 384
#define D_H 64
#define NHEADS 4
#define NSPLIT 4
#define N_CLS 6
#define LN_EPS 1e-5f

typedef __attribute__((ext_vector_type(8))) short short8;
typedef __attribute__((ext_vector_type(4))) float f32x4;

#define L2E2 2.08136898100560774f   /* (log2 e)^2 */

__device__ __forceinline__ unsigned short f2bf(float f) {
    unsigned int u = __float_as_uint(f);
    u += 0x7FFFu + ((u >> 16) & 1u);          // RNE (finite values only here)
    return (unsigned short)(u >> 16);
}
__device__ __forceinline__ float bf2f(unsigned short s) {
    return __uint_as_float(((unsigned int)s) << 16);
}

// Permuted key position within a 64-key tile (pairs bf16 cols for packed LDS
// writes in flash). P-columns and V-rows share the bijection -> PV invariant.
__device__ __forceinline__ int kperm(int k) {
    return (k & 32) + 2 * (k & 15) + ((k >> 4) & 1);
}

// Direct global->LDS 16B copy. LDS dest must be wave-uniform base + lane*16
// (ours is: tid*16 => wave base + lane*16). Global source is per-lane, so
// swizzled LDS layouts are made by pre-swizzling the SOURCE (rule 21).
__device__ __forceinline__ void gload_lds16(const void* g, void* l) {
    __builtin_amdgcn_global_load_lds(
        (const __attribute__((address_space(1))) unsigned int*)g,
        (__attribute__((address_space(3))) unsigned int*)l, 16, 0, 0);
}

// ---------------------------------------------------------------------------
// Fused stage 1 (r9's proven version). 256 blocks x 512 thr:
// phase 1: 8 waves x 4 rows each -> h in LDS; phase 2: wave wv -> head wv>>1,
// half wv&1 (16 rows). Outputs: hp bf16 coalesced; Vf bf16 key-permuted
// coalesced b128; ssq2 = (sum hp^2)*(log2 e)^2.
// NO cooperative / fence / finisher variants: r10 (grid.sync) and r12
// (per-block threadfence) both flushed L2 device-wide and lost 2-3x.
// ---------------------------------------------------------------------------
__global__ __launch_bounds__(512) void stage1_kernel(
    const float* __restrict__ x, const float* __restrict__ proj_w,
    const float* __restrict__ proj_b, const float* __restrict__ head_w,
    const float* __restrict__ head_b,
    unsigned short* __restrict__ hp, unsigned short* __restrict__ Vf,
    float* __restrict__ ssq2)
{
    const int lane = threadIdx.x & 63;
    const int wv   = threadIdx.x >> 6;       // 0..7
    const int rb0  = blockIdx.x * 32;

    __shared__ float h_sh[32][68];                          // [row][feat]
    __shared__ __align__(16) unsigned short vt[NHEADS][4][64][8];

    // ---- phase 1: h = relu(x @ proj_w + b), 4 rows per wave ----
    {
        float acc[4];
        float b = proj_b[lane];
        #pragma unroll
        for (int r = 0; r < 4; ++r) acc[r] = b;
        const float* x0 = x + (size_t)(rb0 + wv * 4) * D_IN;
        #pragma unroll 2
        for (int k4 = 0; k4 < D_IN / 4; ++k4) {
            float w0 = proj_w[(k4 * 4 + 0) * 64 + lane];
            float w1 = proj_w[(k4 * 4 + 1) * 64 + lane];
            float w2 = proj_w[(k4 * 4 + 2) * 64 + lane];
            float w3 = proj_w[(k4 * 4 + 3) * 64 + lane];
            #pragma unroll
            for (int r = 0; r < 4; ++r) {
                float4 xv = *(const float4*)(x0 + r * D_IN + k4 * 4); // wave-uniform
                acc[r] = fmaf(xv.x, w0, acc[r]);
                acc[r] = fmaf(xv.y, w1, acc[r]);
                acc[r] = fmaf(xv.z, w2, acc[r]);
                acc[r] = fmaf(xv.w, w3, acc[r]);
            }
        }
        #pragma unroll
        for (int r = 0; r < 4; ++r)
            h_sh[wv * 4 + r][lane] = fmaxf(acc[r], 0.f);
    }
    __syncthreads();

    // ---- phase 2: hp = h @ head_w[head] + head_b[head]; 16 rows per wave ----
    const int head = wv >> 1;
    const int half = wv & 1;
    float a[16];
    {
        float b = head_b[head * 64 + lane];
        #pragma unroll
        for (int r = 0; r < 16; ++r) a[r] = b;
    }
    const float* wb = head_w + head * 64 * 64;
    #pragma unroll 2
    for (int e4 = 0; e4 < 16; ++e4) {
        float w0 = wb[(e4 * 4 + 0) * 64 + lane];
        float w1 = wb[(e4 * 4 + 1) * 64 + lane];
        float w2 = wb[(e4 * 4 + 2) * 64 + lane];
        float w3 = wb[(e4 * 4 + 3) * 64 + lane];
        #pragma unroll
        for (int r = 0; r < 16; ++r) {
            float4 hv = *(const float4*)&h_sh[half * 16 + r][e4 * 4]; // uniform b128
            a[r] = fmaf(hv.x, w0, a[r]);
            a[r] = fmaf(hv.y, w1, a[r]);
            a[r] = fmaf(hv.z, w2, a[r]);
            a[r] = fmaf(hv.w, w3, a[r]);
        }
    }

    #pragma unroll
    for (int r = 0; r < 16; ++r) {
        int kl  = half * 16 + r;
        int row = rb0 + kl;
        unsigned short hb = f2bf(a[r]);
        float hf = bf2f(hb);
        hp[((size_t)head * N_TOK + row) * 64 + lane] = hb;
        int p = kperm(row & 63);              // halves write disjoint even/odd
        vt[head][(p >> 3) & 3][lane][p & 7] = hb;
        float s = hf * hf;
        #pragma unroll
        for (int off = 32; off > 0; off >>= 1) s += __shfl_xor(s, off);
        if (lane == 0) ssq2[head * N_TOK + row] = s * L2E2;
    }
    __syncthreads();

    // ---- write Vf coalesced: 1024 chunks of 16B, 2 per thread ----
    const int kgbase = (rb0 & 32) ? 4 : 0;
    #pragma unroll
    for (int i = 0; i < 2; ++i) {
        int c  = threadIdx.x + 512 * i;
        int hc = c >> 8, rem = c & 255;
        int kg = rem >> 6, d = rem & 63;
        short8 v = *(const short8*)&vt[hc][kg][d][0];
        *(short8*)&Vf[(((size_t)hc * (N_TOK / 8) + (rb0 >> 6) * 8 + kgbase + kg) * 64
                       + d) * 8] = v;
    }
}

// ---------------------------------------------------------------------------
// Flash distance-attention, 40KB s-major double-buffered build. Journal:
//  r14: 16-row waves REGRESSED 1.84x (never shrink per-wave tile).
//  r15/r16: global-load reorders neutral/worse (L2 window thrash).
//  r17 (127us): LDS staging 50KB dbuf, 1 barrier, 3 blk/CU.
//  r18 (116us): 32KB single-buf, gload_lds+swizzles, 4 blk/CU, 0 conflicts,
//       but 2 barriers/tile + K cover = PV only.
//  r19 (127us): K/V dbuf 1-barrier BUT Psh=16KB (arith error) -> 48KB ->
//       3 blk/CU + 25% grid tail. Schedule fine; capacity killed it.
// This round: same 1-barrier dbuf schedule at EXACTLY 40KB: Psh cut 16->8KB
// via S-MAJOR processing (per ktile: s=0 QK->softmax->PV, then s=1, sharing
// one [16][64] P-buffer; same-wave LDS ops are in-order so no extra sync).
// Cost: K-frags + bV re-read per s (+16 ds_read_b128/tile, ~9% issue; LDS BW
// still << 128B/clk/CU). LDS 8+16+16 = 40960; 4x40960 = 163840 = full 160KiB
// -> 4 blk/CU, no tail, zero conflicts, full-tile staging cover.
// Max logit 0 (diagonal) -> no online rescaling. p = exp2(-sqrt(sq'));
// P packed bf16 pairs (kperm); O bf16. Grid 16 combos x 64 qblocks = 1024
// = 4 blk/CU exact; one head per XCD (xcd = combo&7).
// Go/no-go: flash < 116us else revert to r18; VGPR must stay <=128 no-spill.
// ---------------------------------------------------------------------------
__global__ __launch_bounds__(256, 4) void flash_kernel(
    const unsigned short* __restrict__ hp, const unsigned short* __restrict__ Vf,
    const float* __restrict__ ssq2, unsigned short* __restrict__ Og,
    float* __restrict__ Lg)
{
    const int head  = blockIdx.x & 3;        // combo = split*NHEADS+head
    const int split = blockIdx.x >> 2;       // 0..3
    const int q0    = blockIdx.y * 128;
    const int w     = threadIdx.x >> 6;
    const int lane  = threadIdx.x & 63;
    const int col   = lane & 15;
    const int quad  = lane >> 4;
    const int tid   = threadIdx.x;

    __shared__ __align__(16) unsigned short Psh[4][16][64];    // one s-tile/wave
    __shared__ __align__(16) unsigned short Kst[2][4096];      // swizzled content
    __shared__ __align__(16) unsigned short Vst[2][4096];      // linear (Vf order)

    const unsigned short* hpH = hp + head * (N_TOK * 64);
    const unsigned short* VfH = Vf + head * (N_TOK * 64);
    const float* ssqH = ssq2 + head * N_TOK;

    const int rb = q0 + w * 32;              // this wave's 32 q-rows

    short8 aQ[2][2];
    float ssqn2[2][4];
    #pragma unroll
    for (int s = 0; s < 2; ++s) {
        const unsigned short* qrow = hpH + (rb + s * 16 + col) * 64;
        aQ[s][0] = *(const short8*)(qrow + quad * 8);
        aQ[s][1] = *(const short8*)(qrow + 32 + quad * 8);
        #pragma unroll
        for (int r = 0; r < 4; ++r)
            ssqn2[s][r] = ssqH[rb + s * 16 + quad * 4 + r];
    }

    const f32x4 zero4 = {0.f, 0.f, 0.f, 0.f};
    f32x4 accO[2][4] = {{zero4, zero4, zero4, zero4}, {zero4, zero4, zero4, zero4}};
    f32x4 accL[2] = {zero4, zero4};
    const short8 ones = {16256,16256,16256,16256,16256,16256,16256,16256}; // bf16 1.0
    const float NEG2L2 = -2.0f * L2E2;

    // Staging: LDS chunk c linear; global source chunk = swz(c) (involution).
    const int koff0 = (((tid & ~7) | ((tid & 7) ^ ((tid >> 3) & 7))) << 4);
    // K/P read base (swizzled): row=col, chunk quad -> quad^(col&7). ^64 = +4 chunks.
    const int karow = col * 128 + ((quad ^ (col & 7)) << 4);
    const int va    = (quad * 64 + col) << 4;                  // V chunk base
    // Psh write base: row=quad*4+r, chunk (col>>2)^(row&7); +r*128 and ^(r<<4).
    const int wcb   = quad * 512 + ((((col >> 2) ^ ((quad & 1) << 2)) << 4))
                      + ((col & 3) << 2);

    const int kt0   = split * 32;
    const int ktend = kt0 + 32;

    // ---- prologue: stage K(kt0)+V(kt0) -> buf 0; latency exposed once ----
    {
        const char* kg = (const char*)(hpH + kt0 * 4096);
        const char* vg = (const char*)(VfH + kt0 * 4096);
        gload_lds16(kg + koff0,        (char*)&Kst[0][0] + tid * 16);
        gload_lds16(kg + koff0 + 4096, (char*)&Kst[0][0] + tid * 16 + 4096);
        gload_lds16(vg + tid * 16,        (char*)&Vst[0][0] + tid * 16);
        gload_lds16(vg + tid * 16 + 4096, (char*)&Vst[0][0] + tid * 16 + 4096);
    }
    float smc[4];
    #pragma unroll
    for (int nt = 0; nt < 4; ++nt) smc[nt] = ssqH[kt0 * 64 + nt * 16 + col];
    __syncthreads();

    #pragma unroll 1
    for (int kt = kt0; kt < ktend; ++kt) {
        const int p = (kt - kt0) & 1;
        const char* Kb = (const char*)&Kst[p][0];
        const char* Vb = (const char*)&Vst[p][0];
        const bool has_next = (kt + 1 < ktend);

        // ---- stage K(kt+1)+V(kt+1) -> other buffer; drained at END barrier.
        //      Cover = the whole tile body. ----
        float smn[4];
        if (has_next) {
            const char* kgn = (const char*)(hpH + (kt + 1) * 4096);
            const char* vgn = (const char*)(VfH + (kt + 1) * 4096);
            char* Kn = (char*)&Kst[p ^ 1][0];
            char* Vn = (char*)&Vst[p ^ 1][0];
            gload_lds16(kgn + koff0,        Kn + tid * 16);
            gload_lds16(kgn + koff0 + 4096, Kn + tid * 16 + 4096);
            gload_lds16(vgn + tid * 16,        Vn + tid * 16);
            gload_lds16(vgn + tid * 16 + 4096, Vn + tid * 16 + 4096);
            #pragma unroll
            for (int nt = 0; nt < 4; ++nt)
                smn[nt] = ssqH[(kt + 1) * 64 + nt * 16 + col];
        }

        char* pB = (char*)&Psh[w][0][0];

        // ================= s-major: QK -> softmax -> PV per s ==============
        #pragma unroll
        for (int s = 0; s < 2; ++s) {
            // ---- QK: S[s-tile][keys 0..63], K frags from LDS ----
            f32x4 aS[4] = {zero4, zero4, zero4, zero4};
            {
                short8 k0 = *(const short8*)(Kb + karow);
                short8 k1 = *(const short8*)(Kb + (karow ^ 64));
                short8 k2 = *(const short8*)(Kb + 2048 + karow);
                short8 k3 = *(const short8*)(Kb + 2048 + (karow ^ 64));
                aS[0] = __builtin_amdgcn_mfma_f32_16x16x32_bf16(aQ[s][0], k0, aS[0], 0, 0, 0);
                aS[0] = __builtin_amdgcn_mfma_f32_16x16x32_bf16(aQ[s][1], k1, aS[0], 0, 0, 0);
                aS[1] = __builtin_amdgcn_mfma_f32_16x16x32_bf16(aQ[s][0], k2, aS[1], 0, 0, 0);
                aS[1] = __builtin_amdgcn_mfma_f32_16x16x32_bf16(aQ[s][1], k3, aS[1], 0, 0, 0);
                k0 = *(const short8*)(Kb + 4096 + karow);
                k1 = *(const short8*)(Kb + 4096 + (karow ^ 64));
                k2 = *(const short8*)(Kb + 6144 + karow);
                k3 = *(const short8*)(Kb + 6144 + (karow ^ 64));
                aS[2] = __builtin_amdgcn_mfma_f32_16x16x32_bf16(aQ[s][0], k0, aS[2], 0, 0, 0);
                aS[2] = __builtin_amdgcn_mfma_f32_16x16x32_bf16(aQ[s][1], k1, aS[2], 0, 0, 0);
                aS[3] = __builtin_amdgcn_mfma_f32_16x16x32_bf16(aQ[s][0], k2, aS[3], 0, 0, 0);
                aS[3] = __builtin_amdgcn_mfma_f32_16x16x32_bf16(aQ[s][1], k3, aS[3], 0, 0, 0);
            }

            // ---- softmax: full 64-key row for this s ----
            {
                float pf[4][4];
                #pragma unroll
                for (int nt = 0; nt < 4; ++nt)
                    #pragma unroll
                    for (int r = 0; r < 4; ++r) {
                        float sq = fmaf(aS[nt][r], NEG2L2, ssqn2[s][r] + smc[nt]);
                        pf[nt][r] = __builtin_amdgcn_exp2f(
                            -__builtin_amdgcn_sqrtf(fmaxf(sq, 0.f)));
                    }
                #pragma unroll
                for (int r = 0; r < 4; ++r) {
                    int ad = (wcb ^ (r << 4)) + r * 128;
                    unsigned int d0 = __builtin_amdgcn_perm(__float_as_uint(pf[1][r]),
                                                            __float_as_uint(pf[0][r]), 0x07060302u);
                    *(unsigned int*)(pB + ad) = d0;
                    unsigned int d1 = __builtin_amdgcn_perm(__float_as_uint(pf[3][r]),
                                                            __float_as_uint(pf[2][r]), 0x07060302u);
                    *(unsigned int*)(pB + (ad ^ 64)) = d1;
                }
            }
            // diag tile: force p=1.0 exactly for this s-tile
            if (kt == (rb >> 6) && lane < 16) {
                int t = ((rb + s * 16) >> 4) & 3;
                int ad = lane * 128 + (((lane >> 2) ^ (lane & 7)) << 4)
                         + ((4 * lane + 2 * (t & 1)) & 15);
                if (t & 2) ad ^= 64;
                *(unsigned short*)(pB + ad) = 0x3F80;
            }

            // ---- PV for this s (same-wave LDS order: writes above are seen) ----
            {
                short8 aP = *(const short8*)(pB + karow);
                short8 bV[4];
                #pragma unroll
                for (int dt = 0; dt < 4; ++dt)
                    bV[dt] = *(const short8*)(Vb + va + dt * 256);
                accL[s] = __builtin_amdgcn_mfma_f32_16x16x32_bf16(aP, ones, accL[s], 0, 0, 0);
                #pragma unroll
                for (int dt = 0; dt < 4; ++dt)
                    accO[s][dt] = __builtin_amdgcn_mfma_f32_16x16x32_bf16(aP, bV[dt], accO[s][dt], 0, 0, 0);

                short8 aPb = *(const short8*)(pB + (karow ^ 64));
                #pragma unroll
                for (int dt = 0; dt < 4; ++dt)
                    bV[dt] = *(const short8*)(Vb + va + dt * 256 + 4096);
                accL[s] = __builtin_amdgcn_mfma_f32_16x16x32_bf16(aPb, ones, accL[s], 0, 0, 0);
                #pragma unroll
                for (int dt = 0; dt < 4; ++dt)
                    accO[s][dt] = __builtin_amdgcn_mfma_f32_16x16x32_bf16(aPb, bV[dt], accO[s][dt], 0, 0, 0);
            }
        }

        // ---- END barrier: drains next-tile staging; frees this buffer ----
        __syncthreads();
        if (has_next) {
            smc[0] = smn[0]; smc[1] = smn[1]; smc[2] = smn[2]; smc[3] = smn[3];
        }
    }

    // ---- epilogue: unnormalized O (bf16) and l (f32) for this split ----
    unsigned short* og = Og + (size_t)(split * NHEADS + head) * N_TOK * 64;
    float* lg = Lg + (size_t)(split * NHEADS + head) * N_TOK;
    #pragma unroll
    for (int s = 0; s < 2; ++s)
        #pragma unroll
        for (int r = 0; r < 4; ++r) {
            int row = rb + s * 16 + quad * 4 + r;
            #pragma unroll
            for (int dt = 0; dt < 4; ++dt)
                og[row * 64 + dt * 16 + col] = f2bf(accO[s][dt][r]);
            if (col == 0) lg[row] = accL[s][r];
        }
}

// ---------------------------------------------------------------------------
// Combine: merge NSPLIT splits, head-softmax mix, layernorm, FC. Wave per row.
// ---------------------------------------------------------------------------
__global__ __launch_bounds__(256) void combine_kernel(
    const unsigned short* __restrict__ Og, const float* __restrict__ Lg,
    const float* __restrict__ attn_w, const float* __restrict__ gamma,
    const float* __restrict__ beta, const float* __restrict__ fc_w,
    const float* __restrict__ fc_b, float* __restrict__ out)
{
    const int lane = threadIdx.x & 63;
    const int ty   = threadIdx.x >> 6;
    const int row  = blockIdx.x * 4 + ty;

    float a0 = attn_w[0], a1 = attn_w[1], a2 = attn_w[2], a3 = attn_w[3];
    float m = fmaxf(fmaxf(a0, a1), fmaxf(a2, a3));
    float e0 = __expf(a0 - m), e1 = __expf(a1 - m), e2 = __expf(a2 - m), e3 = __expf(a3 - m);
    float inv = 1.f / (e0 + e1 + e2 + e3);
    float aw[4] = {e0 * inv, e1 * inv, e2 * inv, e3 * inv};

    float c = 0.f;
    #pragma unroll
    for (int hh = 0; hh < NHEADS; ++hh) {
        float l = 0.f, o = 0.f;
        #pragma unroll
        for (int s = 0; s < NSPLIT; ++s) {
            l += Lg[(s * NHEADS + hh) * N_TOK + row];
            o += bf2f(Og[(size_t)((s * NHEADS + hh) * N_TOK + row) * 64 + lane]);
        }
        c += aw[hh] * o * __builtin_amdgcn_rcpf(l);
    }

    float s = c;
    #pragma unroll
    for (int off = 32; off > 0; off >>= 1) s += __shfl_xor(s, off);
    float mu = s * (1.f / 64.f);
    float d = c - mu;
    float v = d * d;
    #pragma unroll
    for (int off = 32; off > 0; off >>= 1) v += __shfl_xor(v, off);
    float normed = d * rsqrtf(v * (1.f / 64.f) + LN_EPS) * gamma[lane] + beta[lane];

    float lg[N_CLS];
    #pragma unroll
    for (int cc = 0; cc < N_CLS; ++cc) {
        float p = normed * fc_w[lane * N_CLS + cc];
        #pragma unroll
        for (int off = 32; off > 0; off >>= 1) p += __shfl_xor(p, off);
        lg[cc] = p;
    }
    if (lane == 0) {
        #pragma unroll
        for (int cc = 0; cc < N_CLS; ++cc)
            out[row * N_CLS + cc] = lg[cc] + fc_b[cc];
    }
}

// ---------------------------------------------------------------------------
extern "C" void kernel_launch(void* const* d_in, const int* in_sizes, int n_in,
                              void* d_out, int out_size, void* d_ws, size_t ws_size,
                              hipStream_t stream)
{
    const float* x      = (const float*)d_in[0];
    const float* proj_w = (const float*)d_in[1];
    const float* proj_b = (const float*)d_in[2];
    const float* head_w = (const float*)d_in[3];
    const float* head_b = (const float*)d_in[4];
    const float* attn_w = (const float*)d_in[5];
    const float* gamma  = (const float*)d_in[6];
    const float* beta   = (const float*)d_in[7];
    const float* fc_w   = (const float*)d_in[8];
    const float* fc_b   = (const float*)d_in[9];
    float* out = (float*)d_out;

    char* ws = (char*)d_ws;
    // ws layout (bytes):
    //   hp   bf16 [4][8192][64]        @ 0          (4 MB)
    //   Vf   bf16 [4][1024][64][8]     @ 4 MB       (4 MB, key-permuted)
    //   ssq2 f32  [4][8192]            @ 8 MB       (128 KB)
    //   Og   bf16 [4][4][8192][64]     @ 8M+128K    (16 MB)
    //   Lg   f32  [4][4][8192]         @ 24M+128K   (512 KB)
    unsigned short* hp = (unsigned short*)(ws);
    unsigned short* Vf = (unsigned short*)(ws + (4u << 20));
    float* ssq2 = (float*)(ws + (8u << 20));
    unsigned short* Og = (unsigned short*)(ws + (8u << 20) + (128u << 10));
    float* Lg   = (float*)(ws + (24u << 20) + (128u << 10));

    stage1_kernel<<<N_TOK / 32, 512, 0, stream>>>(x, proj_w, proj_b, head_w, head_b,
                                                  hp, Vf, ssq2);
    dim3 g2(NHEADS * NSPLIT, N_TOK / 128);  // 16 x 64 = 1024 = 4 blocks/CU exact
    flash_kernel<<<g2, 256, 0, stream>>>(hp, Vf, ssq2, Og, Lg);
    combine_kernel<<<N_TOK / 4, 256, 0, stream>>>(Og, Lg, attn_w, gamma, beta,
                                                  fc_w, fc_b, out);
}

// Round 8
// 226.715 us; speedup vs baseline: 1.8482x; 1.8482x over previous
//
#include <hip/hip_runtime.h>

#define N_TOK 8192
#define D_IN 384
#define D_H 64
#define NHEADS 4
#define NSPLIT 4
#define N_CLS 6
#define LN_EPS 1e-5f

typedef __attribute__((ext_vector_type(8))) short short8;
typedef __attribute__((ext_vector_type(4))) float f32x4;

#define L2E2 2.08136898100560774f   /* (log2 e)^2 */

__device__ __forceinline__ unsigned short f2bf(float f) {
    unsigned int u = __float_as_uint(f);
    u += 0x7FFFu + ((u >> 16) & 1u);          // RNE (finite values only here)
    return (unsigned short)(u >> 16);
}
__device__ __forceinline__ float bf2f(unsigned short s) {
    return __uint_as_float(((unsigned int)s) << 16);
}

// Permuted key position within a 64-key tile (pairs bf16 cols for packed LDS
// writes in flash). P-columns and V-rows share the bijection -> PV invariant.
__device__ __forceinline__ int kperm(int k) {
    return (k & 32) + 2 * (k & 15) + ((k >> 4) & 1);
}

// Direct global->LDS 16B copy. LDS dest must be wave-uniform base + lane*16
// (ours is: tid*16 => wave base + lane*16). Global source is per-lane, so
// swizzled LDS layouts are made by pre-swizzling the SOURCE (rule 21).
__device__ __forceinline__ void gload_lds16(const void* g, void* l) {
    __builtin_amdgcn_global_load_lds(
        (const __attribute__((address_space(1))) unsigned int*)g,
        (__attribute__((address_space(3))) unsigned int*)l, 16, 0, 0);
}

// ---------------------------------------------------------------------------
// Fused stage 1 (r9's proven version). 256 blocks x 512 thr:
// phase 1: 8 waves x 4 rows each -> h in LDS; phase 2: wave wv -> head wv>>1,
// half wv&1 (16 rows). Outputs: hp bf16 coalesced; Vf bf16 key-permuted
// coalesced b128; ssq2 = (sum hp^2)*(log2 e)^2.
// NO cooperative / fence / finisher variants: r10 (grid.sync) and r12
// (per-block threadfence) both flushed L2 device-wide and lost 2-3x.
// ---------------------------------------------------------------------------
__global__ __launch_bounds__(512) void stage1_kernel(
    const float* __restrict__ x, const float* __restrict__ proj_w,
    const float* __restrict__ proj_b, const float* __restrict__ head_w,
    const float* __restrict__ head_b,
    unsigned short* __restrict__ hp, unsigned short* __restrict__ Vf,
    float* __restrict__ ssq2)
{
    const int lane = threadIdx.x & 63;
    const int wv   = threadIdx.x >> 6;       // 0..7
    const int rb0  = blockIdx.x * 32;

    __shared__ float h_sh[32][68];                          // [row][feat]
    __shared__ __align__(16) unsigned short vt[NHEADS][4][64][8];

    // ---- phase 1: h = relu(x @ proj_w + b), 4 rows per wave ----
    {
        float acc[4];
        float b = proj_b[lane];
        #pragma unroll
        for (int r = 0; r < 4; ++r) acc[r] = b;
        const float* x0 = x + (size_t)(rb0 + wv * 4) * D_IN;
        #pragma unroll 2
        for (int k4 = 0; k4 < D_IN / 4; ++k4) {
            float w0 = proj_w[(k4 * 4 + 0) * 64 + lane];
            float w1 = proj_w[(k4 * 4 + 1) * 64 + lane];
            float w2 = proj_w[(k4 * 4 + 2) * 64 + lane];
            float w3 = proj_w[(k4 * 4 + 3) * 64 + lane];
            #pragma unroll
            for (int r = 0; r < 4; ++r) {
                float4 xv = *(const float4*)(x0 + r * D_IN + k4 * 4); // wave-uniform
                acc[r] = fmaf(xv.x, w0, acc[r]);
                acc[r] = fmaf(xv.y, w1, acc[r]);
                acc[r] = fmaf(xv.z, w2, acc[r]);
                acc[r] = fmaf(xv.w, w3, acc[r]);
            }
        }
        #pragma unroll
        for (int r = 0; r < 4; ++r)
            h_sh[wv * 4 + r][lane] = fmaxf(acc[r], 0.f);
    }
    __syncthreads();

    // ---- phase 2: hp = h @ head_w[head] + head_b[head]; 16 rows per wave ----
    const int head = wv >> 1;
    const int half = wv & 1;
    float a[16];
    {
        float b = head_b[head * 64 + lane];
        #pragma unroll
        for (int r = 0; r < 16; ++r) a[r] = b;
    }
    const float* wb = head_w + head * 64 * 64;
    #pragma unroll 2
    for (int e4 = 0; e4 < 16; ++e4) {
        float w0 = wb[(e4 * 4 + 0) * 64 + lane];
        float w1 = wb[(e4 * 4 + 1) * 64 + lane];
        float w2 = wb[(e4 * 4 + 2) * 64 + lane];
        float w3 = wb[(e4 * 4 + 3) * 64 + lane];
        #pragma unroll
        for (int r = 0; r < 16; ++r) {
            float4 hv = *(const float4*)&h_sh[half * 16 + r][e4 * 4]; // uniform b128
            a[r] = fmaf(hv.x, w0, a[r]);
            a[r] = fmaf(hv.y, w1, a[r]);
            a[r] = fmaf(hv.z, w2, a[r]);
            a[r] = fmaf(hv.w, w3, a[r]);
        }
    }

    #pragma unroll
    for (int r = 0; r < 16; ++r) {
        int kl  = half * 16 + r;
        int row = rb0 + kl;
        unsigned short hb = f2bf(a[r]);
        float hf = bf2f(hb);
        hp[((size_t)head * N_TOK + row) * 64 + lane] = hb;
        int p = kperm(row & 63);              // halves write disjoint even/odd
        vt[head][(p >> 3) & 3][lane][p & 7] = hb;
        float s = hf * hf;
        #pragma unroll
        for (int off = 32; off > 0; off >>= 1) s += __shfl_xor(s, off);
        if (lane == 0) ssq2[head * N_TOK + row] = s * L2E2;
    }
    __syncthreads();

    // ---- write Vf coalesced: 1024 chunks of 16B, 2 per thread ----
    const int kgbase = (rb0 & 32) ? 4 : 0;
    #pragma unroll
    for (int i = 0; i < 2; ++i) {
        int c  = threadIdx.x + 512 * i;
        int hc = c >> 8, rem = c & 255;
        int kg = rem >> 6, d = rem & 63;
        short8 v = *(const short8*)&vt[hc][kg][d][0];
        *(short8*)&Vf[(((size_t)hc * (N_TOK / 8) + (rb0 >> 6) * 8 + kgbase + kg) * 64
                       + d) * 8] = v;
    }
}

// ---------------------------------------------------------------------------
// Flash distance-attention, 40KB s-major 1-barrier build (spill-fixed).
// Journal:
//  r14: 16-row waves REGRESSED 1.84x (never shrink per-wave tile).
//  r15/r16: global-load reorders neutral/worse (L2 window thrash).
//  r17 (127us): LDS staging 50KB dbuf, 1 barrier, 3 blk/CU.
//  r18 (116us): 32KB single-buf, 2 barriers/tile, 4 blk/CU, 0 conflicts.
//  r19 (127us): 1-barrier dbuf but 48KB (Psh arith error) -> 3/CU + tail.
//  r20 (308us): 40KB s-major SPILLED: s-loop unroll let the compiler CSE
//       K/V ds_reads across s (same addresses), extending ~32 VGPRs across
//       PV(s=0); allocator pinned 64 -> scratch. FETCH 6.3GB->689MB/disp.
// This round = r20 + spill fix, schedule unchanged:
//  (1) asm volatile("" ::: "memory") at the END of each s iteration:
//      forbids CSE/hoist of s=1 K/V/P LDS ops across s=0 PV; forces cheap
//      re-reads (+16 ds_read_b128/tile) instead of 32-reg live ranges.
//  (2) softmax pf split in two halves of 8 (d0 then d1), r18-style.
// LDS 8K Psh + 16K Kdbuf + 16K Vdbuf = 40960; 4x40960 = full 160KiB ->
// 4 blk/CU, no tail. One barrier/tile (K(t+1),V(t+1) staged at tile top
// into alternate buffers, drained at END; r19-proven safety).
// GATE: FETCH ~6.3GB & WRITE ~17MB (no spill) else permanent revert to r18.
// Max logit 0 (diagonal) -> no online rescaling. p = exp2(-sqrt(sq'));
// P packed bf16 pairs (kperm); O bf16. Grid 16x64=1024 = 4 blk/CU exact.
// ---------------------------------------------------------------------------
__global__ __launch_bounds__(256, 4) void flash_kernel(
    const unsigned short* __restrict__ hp, const unsigned short* __restrict__ Vf,
    const float* __restrict__ ssq2, unsigned short* __restrict__ Og,
    float* __restrict__ Lg)
{
    const int head  = blockIdx.x & 3;        // combo = split*NHEADS+head
    const int split = blockIdx.x >> 2;       // 0..3
    const int q0    = blockIdx.y * 128;
    const int w     = threadIdx.x >> 6;
    const int lane  = threadIdx.x & 63;
    const int col   = lane & 15;
    const int quad  = lane >> 4;
    const int tid   = threadIdx.x;

    __shared__ __align__(16) unsigned short Psh[4][16][64];    // one s-tile/wave
    __shared__ __align__(16) unsigned short Kst[2][4096];      // swizzled content
    __shared__ __align__(16) unsigned short Vst[2][4096];      // linear (Vf order)

    const unsigned short* hpH = hp + head * (N_TOK * 64);
    const unsigned short* VfH = Vf + head * (N_TOK * 64);
    const float* ssqH = ssq2 + head * N_TOK;

    const int rb = q0 + w * 32;              // this wave's 32 q-rows

    short8 aQ[2][2];
    float ssqn2[2][4];
    #pragma unroll
    for (int s = 0; s < 2; ++s) {
        const unsigned short* qrow = hpH + (rb + s * 16 + col) * 64;
        aQ[s][0] = *(const short8*)(qrow + quad * 8);
        aQ[s][1] = *(const short8*)(qrow + 32 + quad * 8);
        #pragma unroll
        for (int r = 0; r < 4; ++r)
            ssqn2[s][r] = ssqH[rb + s * 16 + quad * 4 + r];
    }

    const f32x4 zero4 = {0.f, 0.f, 0.f, 0.f};
    f32x4 accO[2][4] = {{zero4, zero4, zero4, zero4}, {zero4, zero4, zero4, zero4}};
    f32x4 accL[2] = {zero4, zero4};
    const short8 ones = {16256,16256,16256,16256,16256,16256,16256,16256}; // bf16 1.0
    const float NEG2L2 = -2.0f * L2E2;

    // Staging: LDS chunk c linear; global source chunk = swz(c) (involution).
    const int koff0 = (((tid & ~7) | ((tid & 7) ^ ((tid >> 3) & 7))) << 4);
    // K/P read base (swizzled): row=col, chunk quad -> quad^(col&7). ^64 = +4 chunks.
    const int karow = col * 128 + ((quad ^ (col & 7)) << 4);
    const int va    = (quad * 64 + col) << 4;                  // V chunk base
    // Psh write base: row=quad*4+r, chunk (col>>2)^(row&7); +r*128 and ^(r<<4).
    const int wcb   = quad * 512 + ((((col >> 2) ^ ((quad & 1) << 2)) << 4))
                      + ((col & 3) << 2);

    const int kt0   = split * 32;
    const int ktend = kt0 + 32;

    // ---- prologue: stage K(kt0)+V(kt0) -> buf 0; latency exposed once ----
    {
        const char* kg = (const char*)(hpH + kt0 * 4096);
        const char* vg = (const char*)(VfH + kt0 * 4096);
        gload_lds16(kg + koff0,        (char*)&Kst[0][0] + tid * 16);
        gload_lds16(kg + koff0 + 4096, (char*)&Kst[0][0] + tid * 16 + 4096);
        gload_lds16(vg + tid * 16,        (char*)&Vst[0][0] + tid * 16);
        gload_lds16(vg + tid * 16 + 4096, (char*)&Vst[0][0] + tid * 16 + 4096);
    }
    float smc[4];
    #pragma unroll
    for (int nt = 0; nt < 4; ++nt) smc[nt] = ssqH[kt0 * 64 + nt * 16 + col];
    __syncthreads();

    #pragma unroll 1
    for (int kt = kt0; kt < ktend; ++kt) {
        const int p = (kt - kt0) & 1;
        const char* Kb = (const char*)&Kst[p][0];
        const char* Vb = (const char*)&Vst[p][0];
        const bool has_next = (kt + 1 < ktend);

        // ---- stage K(kt+1)+V(kt+1) -> other buffer; drained at END barrier.
        //      Cover = the whole tile body. ----
        float smn[4];
        if (has_next) {
            const char* kgn = (const char*)(hpH + (kt + 1) * 4096);
            const char* vgn = (const char*)(VfH + (kt + 1) * 4096);
            char* Kn = (char*)&Kst[p ^ 1][0];
            char* Vn = (char*)&Vst[p ^ 1][0];
            gload_lds16(kgn + koff0,        Kn + tid * 16);
            gload_lds16(kgn + koff0 + 4096, Kn + tid * 16 + 4096);
            gload_lds16(vgn + tid * 16,        Vn + tid * 16);
            gload_lds16(vgn + tid * 16 + 4096, Vn + tid * 16 + 4096);
            #pragma unroll
            for (int nt = 0; nt < 4; ++nt)
                smn[nt] = ssqH[(kt + 1) * 64 + nt * 16 + col];
        }

        char* pB = (char*)&Psh[w][0][0];

        // ================= s-major: QK -> softmax -> PV per s ==============
        #pragma unroll
        for (int s = 0; s < 2; ++s) {
            // ---- QK half A: keys 0..31 ----
            f32x4 aS0 = zero4, aS1 = zero4;
            {
                short8 k0 = *(const short8*)(Kb + karow);
                short8 k1 = *(const short8*)(Kb + (karow ^ 64));
                short8 k2 = *(const short8*)(Kb + 2048 + karow);
                short8 k3 = *(const short8*)(Kb + 2048 + (karow ^ 64));
                aS0 = __builtin_amdgcn_mfma_f32_16x16x32_bf16(aQ[s][0], k0, aS0, 0, 0, 0);
                aS0 = __builtin_amdgcn_mfma_f32_16x16x32_bf16(aQ[s][1], k1, aS0, 0, 0, 0);
                aS1 = __builtin_amdgcn_mfma_f32_16x16x32_bf16(aQ[s][0], k2, aS1, 0, 0, 0);
                aS1 = __builtin_amdgcn_mfma_f32_16x16x32_bf16(aQ[s][1], k3, aS1, 0, 0, 0);
            }
            // softmax half A -> d0 (pf live: 8)
            #pragma unroll
            for (int r = 0; r < 4; ++r) {
                float sq0 = fmaf(aS0[r], NEG2L2, ssqn2[s][r] + smc[0]);
                float pf0 = __builtin_amdgcn_exp2f(-__builtin_amdgcn_sqrtf(fmaxf(sq0, 0.f)));
                float sq1 = fmaf(aS1[r], NEG2L2, ssqn2[s][r] + smc[1]);
                float pf1 = __builtin_amdgcn_exp2f(-__builtin_amdgcn_sqrtf(fmaxf(sq1, 0.f)));
                unsigned int d0 = __builtin_amdgcn_perm(__float_as_uint(pf1),
                                                        __float_as_uint(pf0), 0x07060302u);
                *(unsigned int*)(pB + ((wcb ^ (r << 4)) + r * 128)) = d0;
            }

            // ---- QK half B: keys 32..63 ----
            f32x4 aS2 = zero4, aS3 = zero4;
            {
                short8 k0 = *(const short8*)(Kb + 4096 + karow);
                short8 k1 = *(const short8*)(Kb + 4096 + (karow ^ 64));
                short8 k2 = *(const short8*)(Kb + 6144 + karow);
                short8 k3 = *(const short8*)(Kb + 6144 + (karow ^ 64));
                aS2 = __builtin_amdgcn_mfma_f32_16x16x32_bf16(aQ[s][0], k0, aS2, 0, 0, 0);
                aS2 = __builtin_amdgcn_mfma_f32_16x16x32_bf16(aQ[s][1], k1, aS2, 0, 0, 0);
                aS3 = __builtin_amdgcn_mfma_f32_16x16x32_bf16(aQ[s][0], k2, aS3, 0, 0, 0);
                aS3 = __builtin_amdgcn_mfma_f32_16x16x32_bf16(aQ[s][1], k3, aS3, 0, 0, 0);
            }
            // softmax half B -> d1
            #pragma unroll
            for (int r = 0; r < 4; ++r) {
                float sq2 = fmaf(aS2[r], NEG2L2, ssqn2[s][r] + smc[2]);
                float pf2 = __builtin_amdgcn_exp2f(-__builtin_amdgcn_sqrtf(fmaxf(sq2, 0.f)));
                float sq3 = fmaf(aS3[r], NEG2L2, ssqn2[s][r] + smc[3]);
                float pf3 = __builtin_amdgcn_exp2f(-__builtin_amdgcn_sqrtf(fmaxf(sq3, 0.f)));
                unsigned int d1 = __builtin_amdgcn_perm(__float_as_uint(pf3),
                                                        __float_as_uint(pf2), 0x07060302u);
                *(unsigned int*)(pB + (((wcb ^ (r << 4)) + r * 128) ^ 64)) = d1;
            }

            // diag tile: force p=1.0 exactly for this s-tile
            if (kt == (rb >> 6) && lane < 16) {
                int t = ((rb + s * 16) >> 4) & 3;
                int ad = lane * 128 + (((lane >> 2) ^ (lane & 7)) << 4)
                         + ((4 * lane + 2 * (t & 1)) & 15);
                if (t & 2) ad ^= 64;
                *(unsigned short*)(pB + ad) = 0x3F80;
            }

            // ---- PV for this s (same-wave LDS order: writes above are seen) ----
            {
                short8 aP = *(const short8*)(pB + karow);
                short8 bV[4];
                #pragma unroll
                for (int dt = 0; dt < 4; ++dt)
                    bV[dt] = *(const short8*)(Vb + va + dt * 256);
                accL[s] = __builtin_amdgcn_mfma_f32_16x16x32_bf16(aP, ones, accL[s], 0, 0, 0);
                #pragma unroll
                for (int dt = 0; dt < 4; ++dt)
                    accO[s][dt] = __builtin_amdgcn_mfma_f32_16x16x32_bf16(aP, bV[dt], accO[s][dt], 0, 0, 0);

                short8 aPb = *(const short8*)(pB + (karow ^ 64));
                #pragma unroll
                for (int dt = 0; dt < 4; ++dt)
                    bV[dt] = *(const short8*)(Vb + va + dt * 256 + 4096);
                accL[s] = __builtin_amdgcn_mfma_f32_16x16x32_bf16(aPb, ones, accL[s], 0, 0, 0);
                #pragma unroll
                for (int dt = 0; dt < 4; ++dt)
                    accO[s][dt] = __builtin_amdgcn_mfma_f32_16x16x32_bf16(aPb, bV[dt], accO[s][dt], 0, 0, 0);
            }

            // Compiler fence: forbid CSE/hoist of next-s K/V/P LDS ops across
            // this PV (r20's spill source). No instruction emitted.
            asm volatile("" ::: "memory");
        }

        // ---- END barrier: drains next-tile staging; frees this buffer ----
        __syncthreads();
        if (has_next) {
            smc[0] = smn[0]; smc[1] = smn[1]; smc[2] = smn[2]; smc[3] = smn[3];
        }
    }

    // ---- epilogue: unnormalized O (bf16) and l (f32) for this split ----
    unsigned short* og = Og + (size_t)(split * NHEADS + head) * N_TOK * 64;
    float* lg = Lg + (size_t)(split * NHEADS + head) * N_TOK;
    #pragma unroll
    for (int s = 0; s < 2; ++s)
        #pragma unroll
        for (int r = 0; r < 4; ++r) {
            int row = rb + s * 16 + quad * 4 + r;
            #pragma unroll
            for (int dt = 0; dt < 4; ++dt)
                og[row * 64 + dt * 16 + col] = f2bf(accO[s][dt][r]);
            if (col == 0) lg[row] = accL[s][r];
        }
}

// ---------------------------------------------------------------------------
// Combine: merge NSPLIT splits, head-softmax mix, layernorm, FC. Wave per row.
// ---------------------------------------------------------------------------
__global__ __launch_bounds__(256) void combine_kernel(
    const unsigned short* __restrict__ Og, const float* __restrict__ Lg,
    const float* __restrict__ attn_w, const float* __restrict__ gamma,
    const float* __restrict__ beta, const float* __restrict__ fc_w,
    const float* __restrict__ fc_b, float* __restrict__ out)
{
    const int lane = threadIdx.x & 63;
    const int ty   = threadIdx.x >> 6;
    const int row  = blockIdx.x * 4 + ty;

    float a0 = attn_w[0], a1 = attn_w[1], a2 = attn_w[2], a3 = attn_w[3];
    float m = fmaxf(fmaxf(a0, a1), fmaxf(a2, a3));
    float e0 = __expf(a0 - m), e1 = __expf(a1 - m), e2 = __expf(a2 - m), e3 = __expf(a3 - m);
    float inv = 1.f / (e0 + e1 + e2 + e3);
    float aw[4] = {e0 * inv, e1 * inv, e2 * inv, e3 * inv};

    float c = 0.f;
    #pragma unroll
    for (int hh = 0; hh < NHEADS; ++hh) {
        float l = 0.f, o = 0.f;
        #pragma unroll
        for (int s = 0; s < NSPLIT; ++s) {
            l += Lg[(s * NHEADS + hh) * N_TOK + row];
            o += bf2f(Og[(size_t)((s * NHEADS + hh) * N_TOK + row) * 64 + lane]);
        }
        c += aw[hh] * o * __builtin_amdgcn_rcpf(l);
    }

    float s = c;
    #pragma unroll
    for (int off = 32; off > 0; off >>= 1) s += __shfl_xor(s, off);
    float mu = s * (1.f / 64.f);
    float d = c - mu;
    float v = d * d;
    #pragma unroll
    for (int off = 32; off > 0; off >>= 1) v += __shfl_xor(v, off);
    float normed = d * rsqrtf(v * (1.f / 64.f) + LN_EPS) * gamma[lane] + beta[lane];

    float lg[N_CLS];
    #pragma unroll
    for (int cc = 0; cc < N_CLS; ++cc) {
        float p = normed * fc_w[lane * N_CLS + cc];
        #pragma unroll
        for (int off = 32; off > 0; off >>= 1) p += __shfl_xor(p, off);
        lg[cc] = p;
    }
    if (lane == 0) {
        #pragma unroll
        for (int cc = 0; cc < N_CLS; ++cc)
            out[row * N_CLS + cc] = lg[cc] + fc_b[cc];
    }
}

// ---------------------------------------------------------------------------
extern "C" void kernel_launch(void* const* d_in, const int* in_sizes, int n_in,
                              void* d_out, int out_size, void* d_ws, size_t ws_size,
                              hipStream_t stream)
{
    const float* x      = (const float*)d_in[0];
    const float* proj_w = (const float*)d_in[1];
    const float* proj_b = (const float*)d_in[2];
    const float* head_w = (const float*)d_in[3];
    const float* head_b = (const float*)d_in[4];
    const float* attn_w = (const float*)d_in[5];
    const float* gamma  = (const float*)d_in[6];
    const float* beta   = (const float*)d_in[7];
    const float* fc_w   = (const float*)d_in[8];
    const float* fc_b   = (const float*)d_in[9];
    float* out = (float*)d_out;

    char* ws = (char*)d_ws;
    // ws layout (bytes):
    //   hp   bf16 [4][8192][64]        @ 0          (4 MB)
    //   Vf   bf16 [4][1024][64][8]     @ 4 MB       (4 MB, key-permuted)
    //   ssq2 f32  [4][8192]            @ 8 MB       (128 KB)
    //   Og   bf16 [4][4][8192][64]     @ 8M+128K    (16 MB)
    //   Lg   f32  [4][4][8192]         @ 24M+128K   (512 KB)
    unsigned short* hp = (unsigned short*)(ws);
    unsigned short* Vf = (unsigned short*)(ws + (4u << 20));
    float* ssq2 = (float*)(ws + (8u << 20));
    unsigned short* Og = (unsigned short*)(ws + (8u << 20) + (128u << 10));
    float* Lg   = (float*)(ws + (24u << 20) + (128u << 10));

    stage1_kernel<<<N_TOK / 32, 512, 0, stream>>>(x, proj_w, proj_b, head_w, head_b,
                                                  hp, Vf, ssq2);
    dim3 g2(NHEADS * NSPLIT, N_TOK / 128);  // 16 x 64 = 1024 = 4 blocks/CU exact
    flash_kernel<<<g2, 256, 0, stream>>>(hp, Vf, ssq2, Og, Lg);
    combine_kernel<<<N_TOK / 4, 256, 0, stream>>>(Og, Lg, attn_w, gamma, beta,
                                                  fc_w, fc_b, out);
}

// Round 9
// 222.006 us; speedup vs baseline: 1.8874x; 1.0212x over previous
//
#include <hip/hip_runtime.h>

#define N_TOK 8192
#define D_IN 384
#define D_H 64
#define NHEADS 4
#define NSPLIT 4
#define N_CLS 6
#define LN_EPS 1e-5f

typedef __attribute__((ext_vector_type(8))) short short8;
typedef __attribute__((ext_vector_type(4))) float f32x4;

#define L2E2 2.08136898100560774f   /* (log2 e)^2 */

__device__ __forceinline__ unsigned short f2bf(float f) {
    unsigned int u = __float_as_uint(f);
    u += 0x7FFFu + ((u >> 16) & 1u);          // RNE (finite values only here)
    return (unsigned short)(u >> 16);
}
__device__ __forceinline__ float bf2f(unsigned short s) {
    return __uint_as_float(((unsigned int)s) << 16);
}

// Permuted key position within a 64-key tile (pairs bf16 cols for packed LDS
// writes in flash). P-columns and V-rows share the bijection -> PV invariant.
__device__ __forceinline__ int kperm(int k) {
    return (k & 32) + 2 * (k & 15) + ((k >> 4) & 1);
}

// Direct global->LDS 16B copy. LDS dest must be wave-uniform base + lane*16
// (ours is: tid*16 => wave base + lane*16). Global source is per-lane, so
// swizzled LDS layouts are made by pre-swizzling the SOURCE (rule 21).
__device__ __forceinline__ void gload_lds16(const void* g, void* l) {
    __builtin_amdgcn_global_load_lds(
        (const __attribute__((address_space(1))) unsigned int*)g,
        (__attribute__((address_space(3))) unsigned int*)l, 16, 0, 0);
}

// ---------------------------------------------------------------------------
// Fused stage 1 (r9's proven version). 256 blocks x 512 thr:
// phase 1: 8 waves x 4 rows each -> h in LDS; phase 2: wave wv -> head wv>>1,
// half wv&1 (16 rows). Outputs: hp bf16 coalesced; Vf bf16 key-permuted
// coalesced b128; ssq2 = (sum hp^2)*(log2 e)^2.
// NO cooperative / fence / finisher variants: r10 (grid.sync) and r12
// (per-block threadfence) both flushed L2 device-wide and lost 2-3x.
// ---------------------------------------------------------------------------
__global__ __launch_bounds__(512) void stage1_kernel(
    const float* __restrict__ x, const float* __restrict__ proj_w,
    const float* __restrict__ proj_b, const float* __restrict__ head_w,
    const float* __restrict__ head_b,
    unsigned short* __restrict__ hp, unsigned short* __restrict__ Vf,
    float* __restrict__ ssq2)
{
    const int lane = threadIdx.x & 63;
    const int wv   = threadIdx.x >> 6;       // 0..7
    const int rb0  = blockIdx.x * 32;

    __shared__ float h_sh[32][68];                          // [row][feat]
    __shared__ __align__(16) unsigned short vt[NHEADS][4][64][8];

    // ---- phase 1: h = relu(x @ proj_w + b), 4 rows per wave ----
    {
        float acc[4];
        float b = proj_b[lane];
        #pragma unroll
        for (int r = 0; r < 4; ++r) acc[r] = b;
        const float* x0 = x + (size_t)(rb0 + wv * 4) * D_IN;
        #pragma unroll 2
        for (int k4 = 0; k4 < D_IN / 4; ++k4) {
            float w0 = proj_w[(k4 * 4 + 0) * 64 + lane];
            float w1 = proj_w[(k4 * 4 + 1) * 64 + lane];
            float w2 = proj_w[(k4 * 4 + 2) * 64 + lane];
            float w3 = proj_w[(k4 * 4 + 3) * 64 + lane];
            #pragma unroll
            for (int r = 0; r < 4; ++r) {
                float4 xv = *(const float4*)(x0 + r * D_IN + k4 * 4); // wave-uniform
                acc[r] = fmaf(xv.x, w0, acc[r]);
                acc[r] = fmaf(xv.y, w1, acc[r]);
                acc[r] = fmaf(xv.z, w2, acc[r]);
                acc[r] = fmaf(xv.w, w3, acc[r]);
            }
        }
        #pragma unroll
        for (int r = 0; r < 4; ++r)
            h_sh[wv * 4 + r][lane] = fmaxf(acc[r], 0.f);
    }
    __syncthreads();

    // ---- phase 2: hp = h @ head_w[head] + head_b[head]; 16 rows per wave ----
    const int head = wv >> 1;
    const int half = wv & 1;
    float a[16];
    {
        float b = head_b[head * 64 + lane];
        #pragma unroll
        for (int r = 0; r < 16; ++r) a[r] = b;
    }
    const float* wb = head_w + head * 64 * 64;
    #pragma unroll 2
    for (int e4 = 0; e4 < 16; ++e4) {
        float w0 = wb[(e4 * 4 + 0) * 64 + lane];
        float w1 = wb[(e4 * 4 + 1) * 64 + lane];
        float w2 = wb[(e4 * 4 + 2) * 64 + lane];
        float w3 = wb[(e4 * 4 + 3) * 64 + lane];
        #pragma unroll
        for (int r = 0; r < 16; ++r) {
            float4 hv = *(const float4*)&h_sh[half * 16 + r][e4 * 4]; // uniform b128
            a[r] = fmaf(hv.x, w0, a[r]);
            a[r] = fmaf(hv.y, w1, a[r]);
            a[r] = fmaf(hv.z, w2, a[r]);
            a[r] = fmaf(hv.w, w3, a[r]);
        }
    }

    #pragma unroll
    for (int r = 0; r < 16; ++r) {
        int kl  = half * 16 + r;
        int row = rb0 + kl;
        unsigned short hb = f2bf(a[r]);
        float hf = bf2f(hb);
        hp[((size_t)head * N_TOK + row) * 64 + lane] = hb;
        int p = kperm(row & 63);              // halves write disjoint even/odd
        vt[head][(p >> 3) & 3][lane][p & 7] = hb;
        float s = hf * hf;
        #pragma unroll
        for (int off = 32; off > 0; off >>= 1) s += __shfl_xor(s, off);
        if (lane == 0) ssq2[head * N_TOK + row] = s * L2E2;
    }
    __syncthreads();

    // ---- write Vf coalesced: 1024 chunks of 16B, 2 per thread ----
    const int kgbase = (rb0 & 32) ? 4 : 0;
    #pragma unroll
    for (int i = 0; i < 2; ++i) {
        int c  = threadIdx.x + 512 * i;
        int hc = c >> 8, rem = c & 255;
        int kg = rem >> 6, d = rem & 63;
        short8 v = *(const short8*)&vt[hc][kg][d][0];
        *(short8*)&Vf[(((size_t)hc * (N_TOK / 8) + (rb0 >> 6) * 8 + kgbase + kg) * 64
                       + d) * 8] = v;
    }
}

// ---------------------------------------------------------------------------
// Flash distance-attention, r18 structure + K double-buffer (40KB). Journal:
//  r14: 16-row waves REGRESSED 1.84x (never shrink per-wave tile).
//  r15/r16: global-load reorders neutral/worse (L2 window thrash).
//  r17 (127us): LDS staging 50KB dbuf, 1 barrier, 3 blk/CU.
//  r18 (116us): 32KB single-buf, 2 barriers/tile, 4 blk/CU, 0 conflicts.
//       BEST base. Stall audit: K(t+1) issued after MID, cover = PV only
//       (~200cyc) vs ~900cyc HBM -> ~700cyc exposed at END x 32 tiles.
//  r19 (127us): 1-barrier dbuf at 48KB (arith error) -> 3/CU + grid tail.
//  r20 (308us): s-major spilled (CSE across s); r21 fence fix -> 120us:
//       s-major family strictly worse than r18's two-phase. Abandoned.
//  Occupancy is HARD-CAPPED at 4 waves/SIMD for 65-128-reg waves (m69
//       halving); never chase >4 blk/CU at this register class.
// This round: r18 byte-identical per-wave stream, but K DOUBLE-buffered:
// V(t) AND K(t+1) both issued at tile top, both drained at MID under the
// full QK+softmax cover (~1100cyc >= 900 HBM); END becomes a pure-LDS
// barrier with zero outstanding vmem. LDS 16K Psh + 16K Kdbuf + 8K V =
// 40960; 4x40960 = 160KiB exact -> 4 blk/CU, no tail.
// Max logit 0 (diagonal) -> no online rescaling. p = exp2(-sqrt(sq'));
// P packed bf16 pairs (kperm); O bf16. Grid 16x64=1024 = 4 blk/CU exact;
// one head per XCD (xcd = combo&7).
// Go/no-go: flash < 116us else END-drain theory wrong -> pivot to
// stage1/combine (~104us residual).
// ---------------------------------------------------------------------------
__global__ __launch_bounds__(256, 4) void flash_kernel(
    const unsigned short* __restrict__ hp, const unsigned short* __restrict__ Vf,
    const float* __restrict__ ssq2, unsigned short* __restrict__ Og,
    float* __restrict__ Lg)
{
    const int head  = blockIdx.x & 3;        // combo = split*NHEADS+head
    const int split = blockIdx.x >> 2;       // 0..3
    const int q0    = blockIdx.y * 128;
    const int w     = threadIdx.x >> 6;
    const int lane  = threadIdx.x & 63;
    const int col   = lane & 15;
    const int quad  = lane >> 4;
    const int tid   = threadIdx.x;

    __shared__ __align__(16) unsigned short Psh[4][2][16][64]; // XOR-swizzled
    __shared__ __align__(16) unsigned short Kst[2][4096];      // K dbuf, swizzled
    __shared__ __align__(16) unsigned short Vst[4096];         // V single, linear

    const unsigned short* hpH = hp + head * (N_TOK * 64);
    const unsigned short* VfH = Vf + head * (N_TOK * 64);
    const float* ssqH = ssq2 + head * N_TOK;

    const int rb = q0 + w * 32;              // this wave's 32 q-rows
    const bool diag_lo = ((rb >> 5) & 1) == 0;  // both s-tiles hit d0 (else d1)

    short8 aQ[2][2];
    float ssqn2[2][4];
    #pragma unroll
    for (int s = 0; s < 2; ++s) {
        const unsigned short* qrow = hpH + (rb + s * 16 + col) * 64;
        aQ[s][0] = *(const short8*)(qrow + quad * 8);
        aQ[s][1] = *(const short8*)(qrow + 32 + quad * 8);
        #pragma unroll
        for (int r = 0; r < 4; ++r)
            ssqn2[s][r] = ssqH[rb + s * 16 + quad * 4 + r];
    }

    const f32x4 zero4 = {0.f, 0.f, 0.f, 0.f};
    f32x4 accO[2][4] = {{zero4, zero4, zero4, zero4}, {zero4, zero4, zero4, zero4}};
    f32x4 accL[2] = {zero4, zero4};
    const short8 ones = {16256,16256,16256,16256,16256,16256,16256,16256}; // bf16 1.0
    const float NEG2L2 = -2.0f * L2E2;

    // Staging: LDS chunk c linear; global source chunk = swz(c) (involution).
    const int koff0 = (((tid & ~7) | ((tid & 7) ^ ((tid >> 3) & 7))) << 4);
    // K/P read base (swizzled): row=col, chunk quad -> quad^(col&7). ^64 = +4 chunks.
    const int karow = col * 128 + ((quad ^ (col & 7)) << 4);
    const int va    = (quad * 64 + col) << 4;                  // V chunk base
    // Psh write base: row=quad*4+r, chunk (col>>2)^(row&7); +r*128 and ^(r<<4).
    const int wcb   = quad * 512 + ((((col >> 2) ^ ((quad & 1) << 2)) << 4))
                      + ((col & 3) << 2);

    const int kt0   = split * 32;
    const int ktend = kt0 + 32;

    // ---- prologue: stage K(kt0) -> Kst[0]; latency exposed once ----
    {
        const char* kg = (const char*)(hpH + kt0 * 4096);
        gload_lds16(kg + koff0,        (char*)&Kst[0][0] + tid * 16);
        gload_lds16(kg + koff0 + 4096, (char*)&Kst[0][0] + tid * 16 + 4096);
    }
    float smc[4];
    #pragma unroll
    for (int nt = 0; nt < 4; ++nt) smc[nt] = ssqH[kt0 * 64 + nt * 16 + col];
    __syncthreads();

    #pragma unroll 1
    for (int kt = kt0; kt < ktend; ++kt) {
        const int p = (kt - kt0) & 1;
        const char* Kb = (const char*)&Kst[p][0];
        const bool has_next = (kt + 1 < ktend);

        // ---- tile top: issue V(kt) AND K(kt+1); both drain at MID under
        //      the full QK+softmax cover (~1100 cyc >= 900 HBM). Buffers are
        //      free: V reads done by END(kt-1); Kst[p^1] reads done by
        //      MID(kt-1) and END(kt-1) has passed. ----
        {
            const char* vg = (const char*)(VfH + kt * 4096);
            gload_lds16(vg + tid * 16,        (char*)Vst + tid * 16);
            gload_lds16(vg + tid * 16 + 4096, (char*)Vst + tid * 16 + 4096);
        }
        float smn[4];
        if (has_next) {
            const char* kgn = (const char*)(hpH + (kt + 1) * 4096);
            char* Kn = (char*)&Kst[p ^ 1][0];
            gload_lds16(kgn + koff0,        Kn + tid * 16);
            gload_lds16(kgn + koff0 + 4096, Kn + tid * 16 + 4096);
            #pragma unroll
            for (int nt = 0; nt < 4; ++nt)
                smn[nt] = ssqH[(kt + 1) * 64 + nt * 16 + col];
        }

        // ---- half A: S for keys 0..31 (K frags from LDS) ----
        f32x4 aSA[2][2] = {{zero4, zero4}, {zero4, zero4}};
        {
            short8 k0 = *(const short8*)(Kb + karow);
            short8 k1 = *(const short8*)(Kb + (karow ^ 64));
            short8 k2 = *(const short8*)(Kb + 2048 + karow);
            short8 k3 = *(const short8*)(Kb + 2048 + (karow ^ 64));
            aSA[0][0] = __builtin_amdgcn_mfma_f32_16x16x32_bf16(aQ[0][0], k0, aSA[0][0], 0, 0, 0);
            aSA[0][0] = __builtin_amdgcn_mfma_f32_16x16x32_bf16(aQ[0][1], k1, aSA[0][0], 0, 0, 0);
            aSA[1][0] = __builtin_amdgcn_mfma_f32_16x16x32_bf16(aQ[1][0], k0, aSA[1][0], 0, 0, 0);
            aSA[1][0] = __builtin_amdgcn_mfma_f32_16x16x32_bf16(aQ[1][1], k1, aSA[1][0], 0, 0, 0);
            aSA[0][1] = __builtin_amdgcn_mfma_f32_16x16x32_bf16(aQ[0][0], k2, aSA[0][1], 0, 0, 0);
            aSA[0][1] = __builtin_amdgcn_mfma_f32_16x16x32_bf16(aQ[0][1], k3, aSA[0][1], 0, 0, 0);
            aSA[1][1] = __builtin_amdgcn_mfma_f32_16x16x32_bf16(aQ[1][0], k2, aSA[1][1], 0, 0, 0);
            aSA[1][1] = __builtin_amdgcn_mfma_f32_16x16x32_bf16(aQ[1][1], k3, aSA[1][1], 0, 0, 0);
        }

        // softmax A -> d0 (swizzled chunk writes); aSA dies here
        #pragma unroll
        for (int s = 0; s < 2; ++s) {
            char* pB = (char*)&Psh[w][s][0][0];
            float pf0[4], pf1[4];
            #pragma unroll
            for (int r = 0; r < 4; ++r) {
                float sq0 = fmaf(aSA[s][0][r], NEG2L2, ssqn2[s][r] + smc[0]);
                pf0[r] = __builtin_amdgcn_exp2f(-__builtin_amdgcn_sqrtf(fmaxf(sq0, 0.f)));
                float sq1 = fmaf(aSA[s][1][r], NEG2L2, ssqn2[s][r] + smc[1]);
                pf1[r] = __builtin_amdgcn_exp2f(-__builtin_amdgcn_sqrtf(fmaxf(sq1, 0.f)));
            }
            #pragma unroll
            for (int r = 0; r < 4; ++r) {
                unsigned int d0 = __builtin_amdgcn_perm(__float_as_uint(pf1[r]),
                                                        __float_as_uint(pf0[r]), 0x07060302u);
                *(unsigned int*)(pB + ((wcb ^ (r << 4)) + r * 128)) = d0;
            }
        }
        // diag tile, lo half
        if (diag_lo && kt == (rb >> 6) && lane < 16) {
            #pragma unroll
            for (int s = 0; s < 2; ++s) {
                int t = ((rb + s * 16) >> 4) & 3;      // 0 or 1
                int sc2 = 4 * lane + 2 * (t & 1);
                int ad = lane * 128 + (((lane >> 2) ^ (lane & 7)) << 4) + (sc2 & 15);
                *(unsigned short*)((char*)&Psh[w][s][0][0] + ad) = 0x3F80;
            }
        }

        // ---- half B: S for keys 32..63 ----
        f32x4 aSB[2][2] = {{zero4, zero4}, {zero4, zero4}};
        {
            short8 k0 = *(const short8*)(Kb + 4096 + karow);
            short8 k1 = *(const short8*)(Kb + 4096 + (karow ^ 64));
            short8 k2 = *(const short8*)(Kb + 6144 + karow);
            short8 k3 = *(const short8*)(Kb + 6144 + (karow ^ 64));
            aSB[0][0] = __builtin_amdgcn_mfma_f32_16x16x32_bf16(aQ[0][0], k0, aSB[0][0], 0, 0, 0);
            aSB[0][0] = __builtin_amdgcn_mfma_f32_16x16x32_bf16(aQ[0][1], k1, aSB[0][0], 0, 0, 0);
            aSB[1][0] = __builtin_amdgcn_mfma_f32_16x16x32_bf16(aQ[1][0], k0, aSB[1][0], 0, 0, 0);
            aSB[1][0] = __builtin_amdgcn_mfma_f32_16x16x32_bf16(aQ[1][1], k1, aSB[1][0], 0, 0, 0);
            aSB[0][1] = __builtin_amdgcn_mfma_f32_16x16x32_bf16(aQ[0][0], k2, aSB[0][1], 0, 0, 0);
            aSB[0][1] = __builtin_amdgcn_mfma_f32_16x16x32_bf16(aQ[0][1], k3, aSB[0][1], 0, 0, 0);
            aSB[1][1] = __builtin_amdgcn_mfma_f32_16x16x32_bf16(aQ[1][0], k2, aSB[1][1], 0, 0, 0);
            aSB[1][1] = __builtin_amdgcn_mfma_f32_16x16x32_bf16(aQ[1][1], k3, aSB[1][1], 0, 0, 0);
        }

        // softmax B -> d1 (same swizzled addr ^ 64); aSB dies here
        #pragma unroll
        for (int s = 0; s < 2; ++s) {
            char* pB = (char*)&Psh[w][s][0][0];
            float pf2[4], pf3[4];
            #pragma unroll
            for (int r = 0; r < 4; ++r) {
                float sq2 = fmaf(aSB[s][0][r], NEG2L2, ssqn2[s][r] + smc[2]);
                pf2[r] = __builtin_amdgcn_exp2f(-__builtin_amdgcn_sqrtf(fmaxf(sq2, 0.f)));
                float sq3 = fmaf(aSB[s][1][r], NEG2L2, ssqn2[s][r] + smc[3]);
                pf3[r] = __builtin_amdgcn_exp2f(-__builtin_amdgcn_sqrtf(fmaxf(sq3, 0.f)));
            }
            #pragma unroll
            for (int r = 0; r < 4; ++r) {
                unsigned int d1 = __builtin_amdgcn_perm(__float_as_uint(pf3[r]),
                                                        __float_as_uint(pf2[r]), 0x07060302u);
                *(unsigned int*)(pB + (((wcb ^ (r << 4)) + r * 128) ^ 64)) = d1;
            }
        }
        // diag tile, hi half
        if (!diag_lo && kt == (rb >> 6) && lane < 16) {
            #pragma unroll
            for (int s = 0; s < 2; ++s) {
                int t = ((rb + s * 16) >> 4) & 3;      // 2 or 3
                int sc2 = 4 * lane + 2 * (t & 1);
                int ad = (lane * 128 + (((lane >> 2) ^ (lane & 7)) << 4) + (sc2 & 15)) ^ 64;
                *(unsigned short*)((char*)&Psh[w][s][0][0] + ad) = 0x3F80;
            }
        }

        // ---- MID barrier: V(kt) + K(kt+1) landed (vmcnt drain under full
        //      QK+softmax cover); all K(kt) reads complete ----
        __syncthreads();

        // ---- PV c=0 ----
        {
            const char* p0 = (const char*)&Psh[w][0][0][0];
            const char* p1 = (const char*)&Psh[w][1][0][0];
            const char* Vb = (const char*)Vst;
            short8 aP0 = *(const short8*)(p0 + karow);
            short8 aP1 = *(const short8*)(p1 + karow);
            short8 bV[4];
            #pragma unroll
            for (int dt = 0; dt < 4; ++dt)
                bV[dt] = *(const short8*)(Vb + va + dt * 256);
            accL[0] = __builtin_amdgcn_mfma_f32_16x16x32_bf16(aP0, ones, accL[0], 0, 0, 0);
            accL[1] = __builtin_amdgcn_mfma_f32_16x16x32_bf16(aP1, ones, accL[1], 0, 0, 0);
            #pragma unroll
            for (int dt = 0; dt < 4; ++dt) {
                accO[0][dt] = __builtin_amdgcn_mfma_f32_16x16x32_bf16(aP0, bV[dt], accO[0][dt], 0, 0, 0);
                accO[1][dt] = __builtin_amdgcn_mfma_f32_16x16x32_bf16(aP1, bV[dt], accO[1][dt], 0, 0, 0);
            }
            // ---- PV c=1 ----
            short8 aP0b = *(const short8*)(p0 + (karow ^ 64));
            short8 aP1b = *(const short8*)(p1 + (karow ^ 64));
            #pragma unroll
            for (int dt = 0; dt < 4; ++dt)
                bV[dt] = *(const short8*)(Vb + va + dt * 256 + 4096);
            accL[0] = __builtin_amdgcn_mfma_f32_16x16x32_bf16(aP0b, ones, accL[0], 0, 0, 0);
            accL[1] = __builtin_amdgcn_mfma_f32_16x16x32_bf16(aP1b, ones, accL[1], 0, 0, 0);
            #pragma unroll
            for (int dt = 0; dt < 4; ++dt) {
                accO[0][dt] = __builtin_amdgcn_mfma_f32_16x16x32_bf16(aP0b, bV[dt], accO[0][dt], 0, 0, 0);
                accO[1][dt] = __builtin_amdgcn_mfma_f32_16x16x32_bf16(aP1b, bV[dt], accO[1][dt], 0, 0, 0);
            }
        }

        // ---- END barrier: pure-LDS sync (no outstanding vmem here);
        //      frees Vst + Psh for next tile top ----
        __syncthreads();
        if (has_next) {
            smc[0] = smn[0]; smc[1] = smn[1]; smc[2] = smn[2]; smc[3] = smn[3];
        }
    }

    // ---- epilogue: unnormalized O (bf16) and l (f32) for this split ----
    unsigned short* og = Og + (size_t)(split * NHEADS + head) * N_TOK * 64;
    float* lg = Lg + (size_t)(split * NHEADS + head) * N_TOK;
    #pragma unroll
    for (int s = 0; s < 2; ++s)
        #pragma unroll
        for (int r = 0; r < 4; ++r) {
            int row = rb + s * 16 + quad * 4 + r;
            #pragma unroll
            for (int dt = 0; dt < 4; ++dt)
                og[row * 64 + dt * 16 + col] = f2bf(accO[s][dt][r]);
            if (col == 0) lg[row] = accL[s][r];
        }
}

// ---------------------------------------------------------------------------
// Combine: merge NSPLIT splits, head-softmax mix, layernorm, FC. Wave per row.
// ---------------------------------------------------------------------------
__global__ __launch_bounds__(256) void combine_kernel(
    const unsigned short* __restrict__ Og, const float* __restrict__ Lg,
    const float* __restrict__ attn_w, const float* __restrict__ gamma,
    const float* __restrict__ beta, const float* __restrict__ fc_w,
    const float* __restrict__ fc_b, float* __restrict__ out)
{
    const int lane = threadIdx.x & 63;
    const int ty   = threadIdx.x >> 6;
    const int row  = blockIdx.x * 4 + ty;

    float a0 = attn_w[0], a1 = attn_w[1], a2 = attn_w[2], a3 = attn_w[3];
    float m = fmaxf(fmaxf(a0, a1), fmaxf(a2, a3));
    float e0 = __expf(a0 - m), e1 = __expf(a1 - m), e2 = __expf(a2 - m), e3 = __expf(a3 - m);
    float inv = 1.f / (e0 + e1 + e2 + e3);
    float aw[4] = {e0 * inv, e1 * inv, e2 * inv, e3 * inv};

    float c = 0.f;
    #pragma unroll
    for (int hh = 0; hh < NHEADS; ++hh) {
        float l = 0.f, o = 0.f;
        #pragma unroll
        for (int s = 0; s < NSPLIT; ++s) {
            l += Lg[(s * NHEADS + hh) * N_TOK + row];
            o += bf2f(Og[(size_t)((s * NHEADS + hh) * N_TOK + row) * 64 + lane]);
        }
        c += aw[hh] * o * __builtin_amdgcn_rcpf(l);
    }

    float s = c;
    #pragma unroll
    for (int off = 32; off > 0; off >>= 1) s += __shfl_xor(s, off);
    float mu = s * (1.f / 64.f);
    float d = c - mu;
    float v = d * d;
    #pragma unroll
    for (int off = 32; off > 0; off >>= 1) v += __shfl_xor(v, off);
    float normed = d * rsqrtf(v * (1.f / 64.f) + LN_EPS) * gamma[lane] + beta[lane];

    float lg[N_CLS];
    #pragma unroll
    for (int cc = 0; cc < N_CLS; ++cc) {
        float p = normed * fc_w[lane * N_CLS + cc];
        #pragma unroll
        for (int off = 32; off > 0; off >>= 1) p += __shfl_xor(p, off);
        lg[cc] = p;
    }
    if (lane == 0) {
        #pragma unroll
        for (int cc = 0; cc < N_CLS; ++cc)
            out[row * N_CLS + cc] = lg[cc] + fc_b[cc];
    }
}

// ---------------------------------------------------------------------------
extern "C" void kernel_launch(void* const* d_in, const int* in_sizes, int n_in,
                              void* d_out, int out_size, void* d_ws, size_t ws_size,
                              hipStream_t stream)
{
    const float* x      = (const float*)d_in[0];
    const float* proj_w = (const float*)d_in[1];
    const float* proj_b = (const float*)d_in[2];
    const float* head_w = (const float*)d_in[3];
    const float* head_b = (const float*)d_in[4];
    const float* attn_w = (const float*)d_in[5];
    const float* gamma  = (const float*)d_in[6];
    const float* beta   = (const float*)d_in[7];
    const float* fc_w   = (const float*)d_in[8];
    const float* fc_b   = (const float*)d_in[9];
    float* out = (float*)d_out;

    char* ws = (char*)d_ws;
    // ws layout (bytes):
    //   hp   bf16 [4][8192][64]        @ 0          (4 MB)
    //   Vf   bf16 [4][1024][64][8]     @ 4 MB       (4 MB, key-permuted)
    //   ssq2 f32  [4][8192]            @ 8 MB       (128 KB)
    //   Og   bf16 [4][4][8192][64]     @ 8M+128K    (16 MB)
    //   Lg   f32  [4][4][8192]         @ 24M+128K   (512 KB)
    unsigned short* hp = (unsigned short*)(ws);
    unsigned short* Vf = (unsigned short*)(ws + (4u << 20));
    float* ssq2 = (float*)(ws + (8u << 20));
    unsigned short* Og = (unsigned short*)(ws + (8u << 20) + (128u << 10));
    float* Lg   = (float*)(ws + (24u << 20) + (128u << 10));

    stage1_kernel<<<N_TOK / 32, 512, 0, stream>>>(x, proj_w, proj_b, head_w, head_b,
                                                  hp, Vf, ssq2);
    dim3 g2(NHEADS * NSPLIT, N_TOK / 128);  // 16 x 64 = 1024 = 4 blocks/CU exact
    flash_kernel<<<g2, 256, 0, stream>>>(hp, Vf, ssq2, Og, Lg);
    combine_kernel<<<N_TOK / 4, 256, 0, stream>>>(Og, Lg, attn_w, gamma, beta,
                                                  fc_w, fc_b, out);
}

// Round 10
// 215.538 us; speedup vs baseline: 1.9441x; 1.0300x over previous
//
#include <hip/hip_runtime.h>

#define N_TOK 8192
#define D_IN 384
#define D_H 64
#define NHEADS 4
#define NSPLIT 4
#define N_CLS 6
#define LN_EPS 1e-5f

typedef __attribute__((ext_vector_type(8))) short short8;
typedef __attribute__((ext_vector_type(4))) float f32x4;

#define L2E2 2.08136898100560774f   /* (log2 e)^2 */

__device__ __forceinline__ unsigned short f2bf(float f) {
    unsigned int u = __float_as_uint(f);
    u += 0x7FFFu + ((u >> 16) & 1u);          // RNE (finite values only here)
    return (unsigned short)(u >> 16);
}
__device__ __forceinline__ float bf2f(unsigned short s) {
    return __uint_as_float(((unsigned int)s) << 16);
}

// Permuted key position within a 64-key tile (pairs bf16 cols for packed LDS
// writes in flash). P-columns and V-rows share the bijection -> PV invariant.
__device__ __forceinline__ int kperm(int k) {
    return (k & 32) + 2 * (k & 15) + ((k >> 4) & 1);
}

// Direct global->LDS 16B copy. LDS dest must be wave-uniform base + lane*16
// (ours is: tid*16 => wave base + lane*16). Global source is per-lane, so
// swizzled LDS layouts are made by pre-swizzling the SOURCE (rule 21).
__device__ __forceinline__ void gload_lds16(const void* g, void* l) {
    __builtin_amdgcn_global_load_lds(
        (const __attribute__((address_space(1))) unsigned int*)g,
        (__attribute__((address_space(3))) unsigned int*)l, 16, 0, 0);
}

// ---------------------------------------------------------------------------
// Fused stage 1 (r9's proven version). 256 blocks x 512 thr:
// phase 1: 8 waves x 4 rows each -> h in LDS; phase 2: wave wv -> head wv>>1,
// half wv&1 (16 rows). Outputs: hp bf16 coalesced; Vf bf16 key-permuted
// coalesced b128; ssq2 = (sum hp^2)*(log2 e)^2.
// NO cooperative / fence / finisher variants: r10 (grid.sync) and r12
// (per-block threadfence) both flushed L2 device-wide and lost 2-3x.
// ---------------------------------------------------------------------------
__global__ __launch_bounds__(512) void stage1_kernel(
    const float* __restrict__ x, const float* __restrict__ proj_w,
    const float* __restrict__ proj_b, const float* __restrict__ head_w,
    const float* __restrict__ head_b,
    unsigned short* __restrict__ hp, unsigned short* __restrict__ Vf,
    float* __restrict__ ssq2)
{
    const int lane = threadIdx.x & 63;
    const int wv   = threadIdx.x >> 6;       // 0..7
    const int rb0  = blockIdx.x * 32;

    __shared__ float h_sh[32][68];                          // [row][feat]
    __shared__ __align__(16) unsigned short vt[NHEADS][4][64][8];

    // ---- phase 1: h = relu(x @ proj_w + b), 4 rows per wave ----
    {
        float acc[4];
        float b = proj_b[lane];
        #pragma unroll
        for (int r = 0; r < 4; ++r) acc[r] = b;
        const float* x0 = x + (size_t)(rb0 + wv * 4) * D_IN;
        #pragma unroll 2
        for (int k4 = 0; k4 < D_IN / 4; ++k4) {
            float w0 = proj_w[(k4 * 4 + 0) * 64 + lane];
            float w1 = proj_w[(k4 * 4 + 1) * 64 + lane];
            float w2 = proj_w[(k4 * 4 + 2) * 64 + lane];
            float w3 = proj_w[(k4 * 4 + 3) * 64 + lane];
            #pragma unroll
            for (int r = 0; r < 4; ++r) {
                float4 xv = *(const float4*)(x0 + r * D_IN + k4 * 4); // wave-uniform
                acc[r] = fmaf(xv.x, w0, acc[r]);
                acc[r] = fmaf(xv.y, w1, acc[r]);
                acc[r] = fmaf(xv.z, w2, acc[r]);
                acc[r] = fmaf(xv.w, w3, acc[r]);
            }
        }
        #pragma unroll
        for (int r = 0; r < 4; ++r)
            h_sh[wv * 4 + r][lane] = fmaxf(acc[r], 0.f);
    }
    __syncthreads();

    // ---- phase 2: hp = h @ head_w[head] + head_b[head]; 16 rows per wave ----
    const int head = wv >> 1;
    const int half = wv & 1;
    float a[16];
    {
        float b = head_b[head * 64 + lane];
        #pragma unroll
        for (int r = 0; r < 16; ++r) a[r] = b;
    }
    const float* wb = head_w + head * 64 * 64;
    #pragma unroll 2
    for (int e4 = 0; e4 < 16; ++e4) {
        float w0 = wb[(e4 * 4 + 0) * 64 + lane];
        float w1 = wb[(e4 * 4 + 1) * 64 + lane];
        float w2 = wb[(e4 * 4 + 2) * 64 + lane];
        float w3 = wb[(e4 * 4 + 3) * 64 + lane];
        #pragma unroll
        for (int r = 0; r < 16; ++r) {
            float4 hv = *(const float4*)&h_sh[half * 16 + r][e4 * 4]; // uniform b128
            a[r] = fmaf(hv.x, w0, a[r]);
            a[r] = fmaf(hv.y, w1, a[r]);
            a[r] = fmaf(hv.z, w2, a[r]);
            a[r] = fmaf(hv.w, w3, a[r]);
        }
    }

    #pragma unroll
    for (int r = 0; r < 16; ++r) {
        int kl  = half * 16 + r;
        int row = rb0 + kl;
        unsigned short hb = f2bf(a[r]);
        float hf = bf2f(hb);
        hp[((size_t)head * N_TOK + row) * 64 + lane] = hb;
        int p = kperm(row & 63);              // halves write disjoint even/odd
        vt[head][(p >> 3) & 3][lane][p & 7] = hb;
        float s = hf * hf;
        #pragma unroll
        for (int off = 32; off > 0; off >>= 1) s += __shfl_xor(s, off);
        if (lane == 0) ssq2[head * N_TOK + row] = s * L2E2;
    }
    __syncthreads();

    // ---- write Vf coalesced: 1024 chunks of 16B, 2 per thread ----
    const int kgbase = (rb0 & 32) ? 4 : 0;
    #pragma unroll
    for (int i = 0; i < 2; ++i) {
        int c  = threadIdx.x + 512 * i;
        int hc = c >> 8, rem = c & 255;
        int kg = rem >> 6, d = rem & 63;
        short8 v = *(const short8*)&vt[hc][kg][d][0];
        *(short8*)&Vf[(((size_t)hc * (N_TOK / 8) + (rb0 >> 6) * 8 + kgbase + kg) * 64
                       + d) * 8] = v;
    }
}

// ---------------------------------------------------------------------------
// Flash distance-attention, r22 K-dbuf schedule + VALU cut. Journal:
//  r14: 16-row waves REGRESSED 1.84x (never shrink per-wave tile).
//  r15/r16: global-load reorders neutral/worse (L2 window thrash).
//  r17 (127us): LDS staging 50KB dbuf, 1 barrier, 3 blk/CU.
//  r18 (116us): 32KB single-buf, 2 barriers/tile, 4 blk/CU, 0 conflicts.
//  r19 (127us): 1-barrier dbuf at 48KB (arith error) -> 3/CU + grid tail.
//  r20 (308us): s-major spilled (CSE across s); r21 fence fix 120us: s-major
//       strictly worse than two-phase. Abandoned.
//  r22 (114.6us): K dbuf, V+K(t+1) both staged at tile top, END = pure-LDS.
//       K/V are L2-RESIDENT (head's 2MB fits its XCD L2 via combo&7 map),
//       so staging latency ~200-400cyc, fully covered. VALU-busy = 72.8us
//       of 114.6 wall -> VALU/trans pipe is now the binding resource.
//  Occupancy HARD-CAPPED at 4 waves/SIMD for 65-128-reg waves. Don't chase.
// This round (VALU reduction, schedule untouched):
//  (1) fmaxf(sq,0) -> fabsf(sq): folds into v_sqrt's free input modifier,
//      -32 v_max/tile. Safe: sq<0 only possible where true dist ~ 0 = exact
//      diagonal, whose Psh slot is overwritten with 1.0 before PV anyway
//      (min off-diag dist^2*L2E2 ~ 40 >> rounding ~1).
//  (2) s_setprio(1) around the 3 MFMA bursts (T5): 4 waves/SIMD from 4
//      DESYNCED blocks = role-diversity regime (m191 +4-7%), not lockstep
//      (m190 null). If neutral/regressed, drop setprio next round.
// GATE: absmax must stay 0.015625 exactly; flash < 114.6 else revert piece.
// Max logit 0 (diagonal) -> no online rescaling. p = exp2(-sqrt(sq'));
// P packed bf16 pairs (kperm); O bf16. LDS 16K Psh + 16K Kdbuf + 8K V =
// 40960 = 4 blk/CU exact. Grid 16x64=1024; one head per XCD (combo&7).
// ---------------------------------------------------------------------------
__global__ __launch_bounds__(256, 4) void flash_kernel(
    const unsigned short* __restrict__ hp, const unsigned short* __restrict__ Vf,
    const float* __restrict__ ssq2, unsigned short* __restrict__ Og,
    float* __restrict__ Lg)
{
    const int head  = blockIdx.x & 3;        // combo = split*NHEADS+head
    const int split = blockIdx.x >> 2;       // 0..3
    const int q0    = blockIdx.y * 128;
    const int w     = threadIdx.x >> 6;
    const int lane  = threadIdx.x & 63;
    const int col   = lane & 15;
    const int quad  = lane >> 4;
    const int tid   = threadIdx.x;

    __shared__ __align__(16) unsigned short Psh[4][2][16][64]; // XOR-swizzled
    __shared__ __align__(16) unsigned short Kst[2][4096];      // K dbuf, swizzled
    __shared__ __align__(16) unsigned short Vst[4096];         // V single, linear

    const unsigned short* hpH = hp + head * (N_TOK * 64);
    const unsigned short* VfH = Vf + head * (N_TOK * 64);
    const float* ssqH = ssq2 + head * N_TOK;

    const int rb = q0 + w * 32;              // this wave's 32 q-rows
    const bool diag_lo = ((rb >> 5) & 1) == 0;  // both s-tiles hit d0 (else d1)

    short8 aQ[2][2];
    float ssqn2[2][4];
    #pragma unroll
    for (int s = 0; s < 2; ++s) {
        const unsigned short* qrow = hpH + (rb + s * 16 + col) * 64;
        aQ[s][0] = *(const short8*)(qrow + quad * 8);
        aQ[s][1] = *(const short8*)(qrow + 32 + quad * 8);
        #pragma unroll
        for (int r = 0; r < 4; ++r)
            ssqn2[s][r] = ssqH[rb + s * 16 + quad * 4 + r];
    }

    const f32x4 zero4 = {0.f, 0.f, 0.f, 0.f};
    f32x4 accO[2][4] = {{zero4, zero4, zero4, zero4}, {zero4, zero4, zero4, zero4}};
    f32x4 accL[2] = {zero4, zero4};
    const short8 ones = {16256,16256,16256,16256,16256,16256,16256,16256}; // bf16 1.0
    const float NEG2L2 = -2.0f * L2E2;

    // Staging: LDS chunk c linear; global source chunk = swz(c) (involution).
    const int koff0 = (((tid & ~7) | ((tid & 7) ^ ((tid >> 3) & 7))) << 4);
    // K/P read base (swizzled): row=col, chunk quad -> quad^(col&7). ^64 = +4 chunks.
    const int karow = col * 128 + ((quad ^ (col & 7)) << 4);
    const int va    = (quad * 64 + col) << 4;                  // V chunk base
    // Psh write base: row=quad*4+r, chunk (col>>2)^(row&7); +r*128 and ^(r<<4).
    const int wcb   = quad * 512 + ((((col >> 2) ^ ((quad & 1) << 2)) << 4))
                      + ((col & 3) << 2);

    const int kt0   = split * 32;
    const int ktend = kt0 + 32;

    // ---- prologue: stage K(kt0) -> Kst[0]; latency exposed once ----
    {
        const char* kg = (const char*)(hpH + kt0 * 4096);
        gload_lds16(kg + koff0,        (char*)&Kst[0][0] + tid * 16);
        gload_lds16(kg + koff0 + 4096, (char*)&Kst[0][0] + tid * 16 + 4096);
    }
    float smc[4];
    #pragma unroll
    for (int nt = 0; nt < 4; ++nt) smc[nt] = ssqH[kt0 * 64 + nt * 16 + col];
    __syncthreads();

    #pragma unroll 1
    for (int kt = kt0; kt < ktend; ++kt) {
        const int p = (kt - kt0) & 1;
        const char* Kb = (const char*)&Kst[p][0];
        const bool has_next = (kt + 1 < ktend);

        // ---- tile top: issue V(kt) AND K(kt+1); both drain at MID under
        //      the full QK+softmax cover (L2-resident, ~200-400 cyc). ----
        {
            const char* vg = (const char*)(VfH + kt * 4096);
            gload_lds16(vg + tid * 16,        (char*)Vst + tid * 16);
            gload_lds16(vg + tid * 16 + 4096, (char*)Vst + tid * 16 + 4096);
        }
        float smn[4];
        if (has_next) {
            const char* kgn = (const char*)(hpH + (kt + 1) * 4096);
            char* Kn = (char*)&Kst[p ^ 1][0];
            gload_lds16(kgn + koff0,        Kn + tid * 16);
            gload_lds16(kgn + koff0 + 4096, Kn + tid * 16 + 4096);
            #pragma unroll
            for (int nt = 0; nt < 4; ++nt)
                smn[nt] = ssqH[(kt + 1) * 64 + nt * 16 + col];
        }

        // ---- half A: S for keys 0..31 (K frags from LDS) ----
        f32x4 aSA[2][2] = {{zero4, zero4}, {zero4, zero4}};
        {
            short8 k0 = *(const short8*)(Kb + karow);
            short8 k1 = *(const short8*)(Kb + (karow ^ 64));
            short8 k2 = *(const short8*)(Kb + 2048 + karow);
            short8 k3 = *(const short8*)(Kb + 2048 + (karow ^ 64));
            __builtin_amdgcn_s_setprio(1);
            aSA[0][0] = __builtin_amdgcn_mfma_f32_16x16x32_bf16(aQ[0][0], k0, aSA[0][0], 0, 0, 0);
            aSA[0][0] = __builtin_amdgcn_mfma_f32_16x16x32_bf16(aQ[0][1], k1, aSA[0][0], 0, 0, 0);
            aSA[1][0] = __builtin_amdgcn_mfma_f32_16x16x32_bf16(aQ[1][0], k0, aSA[1][0], 0, 0, 0);
            aSA[1][0] = __builtin_amdgcn_mfma_f32_16x16x32_bf16(aQ[1][1], k1, aSA[1][0], 0, 0, 0);
            aSA[0][1] = __builtin_amdgcn_mfma_f32_16x16x32_bf16(aQ[0][0], k2, aSA[0][1], 0, 0, 0);
            aSA[0][1] = __builtin_amdgcn_mfma_f32_16x16x32_bf16(aQ[0][1], k3, aSA[0][1], 0, 0, 0);
            aSA[1][1] = __builtin_amdgcn_mfma_f32_16x16x32_bf16(aQ[1][0], k2, aSA[1][1], 0, 0, 0);
            aSA[1][1] = __builtin_amdgcn_mfma_f32_16x16x32_bf16(aQ[1][1], k3, aSA[1][1], 0, 0, 0);
            __builtin_amdgcn_s_setprio(0);
        }

        // softmax A -> d0 (swizzled chunk writes); aSA dies here
        #pragma unroll
        for (int s = 0; s < 2; ++s) {
            char* pB = (char*)&Psh[w][s][0][0];
            float pf0[4], pf1[4];
            #pragma unroll
            for (int r = 0; r < 4; ++r) {
                float sq0 = fmaf(aSA[s][0][r], NEG2L2, ssqn2[s][r] + smc[0]);
                pf0[r] = __builtin_amdgcn_exp2f(-__builtin_amdgcn_sqrtf(__builtin_fabsf(sq0)));
                float sq1 = fmaf(aSA[s][1][r], NEG2L2, ssqn2[s][r] + smc[1]);
                pf1[r] = __builtin_amdgcn_exp2f(-__builtin_amdgcn_sqrtf(__builtin_fabsf(sq1)));
            }
            #pragma unroll
            for (int r = 0; r < 4; ++r) {
                unsigned int d0 = __builtin_amdgcn_perm(__float_as_uint(pf1[r]),
                                                        __float_as_uint(pf0[r]), 0x07060302u);
                *(unsigned int*)(pB + ((wcb ^ (r << 4)) + r * 128)) = d0;
            }
        }
        // diag tile, lo half
        if (diag_lo && kt == (rb >> 6) && lane < 16) {
            #pragma unroll
            for (int s = 0; s < 2; ++s) {
                int t = ((rb + s * 16) >> 4) & 3;      // 0 or 1
                int sc2 = 4 * lane + 2 * (t & 1);
                int ad = lane * 128 + (((lane >> 2) ^ (lane & 7)) << 4) + (sc2 & 15);
                *(unsigned short*)((char*)&Psh[w][s][0][0] + ad) = 0x3F80;
            }
        }

        // ---- half B: S for keys 32..63 ----
        f32x4 aSB[2][2] = {{zero4, zero4}, {zero4, zero4}};
        {
            short8 k0 = *(const short8*)(Kb + 4096 + karow);
            short8 k1 = *(const short8*)(Kb + 4096 + (karow ^ 64));
            short8 k2 = *(const short8*)(Kb + 6144 + karow);
            short8 k3 = *(const short8*)(Kb + 6144 + (karow ^ 64));
            __builtin_amdgcn_s_setprio(1);
            aSB[0][0] = __builtin_amdgcn_mfma_f32_16x16x32_bf16(aQ[0][0], k0, aSB[0][0], 0, 0, 0);
            aSB[0][0] = __builtin_amdgcn_mfma_f32_16x16x32_bf16(aQ[0][1], k1, aSB[0][0], 0, 0, 0);
            aSB[1][0] = __builtin_amdgcn_mfma_f32_16x16x32_bf16(aQ[1][0], k0, aSB[1][0], 0, 0, 0);
            aSB[1][0] = __builtin_amdgcn_mfma_f32_16x16x32_bf16(aQ[1][1], k1, aSB[1][0], 0, 0, 0);
            aSB[0][1] = __builtin_amdgcn_mfma_f32_16x16x32_bf16(aQ[0][0], k2, aSB[0][1], 0, 0, 0);
            aSB[0][1] = __builtin_amdgcn_mfma_f32_16x16x32_bf16(aQ[0][1], k3, aSB[0][1], 0, 0, 0);
            aSB[1][1] = __builtin_amdgcn_mfma_f32_16x16x32_bf16(aQ[1][0], k2, aSB[1][1], 0, 0, 0);
            aSB[1][1] = __builtin_amdgcn_mfma_f32_16x16x32_bf16(aQ[1][1], k3, aSB[1][1], 0, 0, 0);
            __builtin_amdgcn_s_setprio(0);
        }

        // softmax B -> d1 (same swizzled addr ^ 64); aSB dies here
        #pragma unroll
        for (int s = 0; s < 2; ++s) {
            char* pB = (char*)&Psh[w][s][0][0];
            float pf2[4], pf3[4];
            #pragma unroll
            for (int r = 0; r < 4; ++r) {
                float sq2 = fmaf(aSB[s][0][r], NEG2L2, ssqn2[s][r] + smc[2]);
                pf2[r] = __builtin_amdgcn_exp2f(-__builtin_amdgcn_sqrtf(__builtin_fabsf(sq2)));
                float sq3 = fmaf(aSB[s][1][r], NEG2L2, ssqn2[s][r] + smc[3]);
                pf3[r] = __builtin_amdgcn_exp2f(-__builtin_amdgcn_sqrtf(__builtin_fabsf(sq3)));
            }
            #pragma unroll
            for (int r = 0; r < 4; ++r) {
                unsigned int d1 = __builtin_amdgcn_perm(__float_as_uint(pf3[r]),
                                                        __float_as_uint(pf2[r]), 0x07060302u);
                *(unsigned int*)(pB + (((wcb ^ (r << 4)) + r * 128) ^ 64)) = d1;
            }
        }
        // diag tile, hi half
        if (!diag_lo && kt == (rb >> 6) && lane < 16) {
            #pragma unroll
            for (int s = 0; s < 2; ++s) {
                int t = ((rb + s * 16) >> 4) & 3;      // 2 or 3
                int sc2 = 4 * lane + 2 * (t & 1);
                int ad = (lane * 128 + (((lane >> 2) ^ (lane & 7)) << 4) + (sc2 & 15)) ^ 64;
                *(unsigned short*)((char*)&Psh[w][s][0][0] + ad) = 0x3F80;
            }
        }

        // ---- MID barrier: V(kt) + K(kt+1) landed; all K(kt) reads done ----
        __syncthreads();

        // ---- PV c=0 ----
        {
            const char* p0 = (const char*)&Psh[w][0][0][0];
            const char* p1 = (const char*)&Psh[w][1][0][0];
            const char* Vb = (const char*)Vst;
            short8 aP0 = *(const short8*)(p0 + karow);
            short8 aP1 = *(const short8*)(p1 + karow);
            short8 bV[4];
            #pragma unroll
            for (int dt = 0; dt < 4; ++dt)
                bV[dt] = *(const short8*)(Vb + va + dt * 256);
            __builtin_amdgcn_s_setprio(1);
            accL[0] = __builtin_amdgcn_mfma_f32_16x16x32_bf16(aP0, ones, accL[0], 0, 0, 0);
            accL[1] = __builtin_amdgcn_mfma_f32_16x16x32_bf16(aP1, ones, accL[1], 0, 0, 0);
            #pragma unroll
            for (int dt = 0; dt < 4; ++dt) {
                accO[0][dt] = __builtin_amdgcn_mfma_f32_16x16x32_bf16(aP0, bV[dt], accO[0][dt], 0, 0, 0);
                accO[1][dt] = __builtin_amdgcn_mfma_f32_16x16x32_bf16(aP1, bV[dt], accO[1][dt], 0, 0, 0);
            }
            __builtin_amdgcn_s_setprio(0);
            // ---- PV c=1 ----
            short8 aP0b = *(const short8*)(p0 + (karow ^ 64));
            short8 aP1b = *(const short8*)(p1 + (karow ^ 64));
            #pragma unroll
            for (int dt = 0; dt < 4; ++dt)
                bV[dt] = *(const short8*)(Vb + va + dt * 256 + 4096);
            __builtin_amdgcn_s_setprio(1);
            accL[0] = __builtin_amdgcn_mfma_f32_16x16x32_bf16(aP0b, ones, accL[0], 0, 0, 0);
            accL[1] = __builtin_amdgcn_mfma_f32_16x16x32_bf16(aP1b, ones, accL[1], 0, 0, 0);
            #pragma unroll
            for (int dt = 0; dt < 4; ++dt) {
                accO[0][dt] = __builtin_amdgcn_mfma_f32_16x16x32_bf16(aP0b, bV[dt], accO[0][dt], 0, 0, 0);
                accO[1][dt] = __builtin_amdgcn_mfma_f32_16x16x32_bf16(aP1b, bV[dt], accO[1][dt], 0, 0, 0);
            }
            __builtin_amdgcn_s_setprio(0);
        }

        // ---- END barrier: pure-LDS sync (no outstanding vmem here);
        //      frees Vst + Psh for next tile top ----
        __syncthreads();
        if (has_next) {
            smc[0] = smn[0]; smc[1] = smn[1]; smc[2] = smn[2]; smc[3] = smn[3];
        }
    }

    // ---- epilogue: unnormalized O (bf16) and l (f32) for this split ----
    unsigned short* og = Og + (size_t)(split * NHEADS + head) * N_TOK * 64;
    float* lg = Lg + (size_t)(split * NHEADS + head) * N_TOK;
    #pragma unroll
    for (int s = 0; s < 2; ++s)
        #pragma unroll
        for (int r = 0; r < 4; ++r) {
            int row = rb + s * 16 + quad * 4 + r;
            #pragma unroll
            for (int dt = 0; dt < 4; ++dt)
                og[row * 64 + dt * 16 + col] = f2bf(accO[s][dt][r]);
            if (col == 0) lg[row] = accL[s][r];
        }
}

// ---------------------------------------------------------------------------
// Combine: merge NSPLIT splits, head-softmax mix, layernorm, FC. Wave per row.
// ---------------------------------------------------------------------------
__global__ __launch_bounds__(256) void combine_kernel(
    const unsigned short* __restrict__ Og, const float* __restrict__ Lg,
    const float* __restrict__ attn_w, const float* __restrict__ gamma,
    const float* __restrict__ beta, const float* __restrict__ fc_w,
    const float* __restrict__ fc_b, float* __restrict__ out)
{
    const int lane = threadIdx.x & 63;
    const int ty   = threadIdx.x >> 6;
    const int row  = blockIdx.x * 4 + ty;

    float a0 = attn_w[0], a1 = attn_w[1], a2 = attn_w[2], a3 = attn_w[3];
    float m = fmaxf(fmaxf(a0, a1), fmaxf(a2, a3));
    float e0 = __expf(a0 - m), e1 = __expf(a1 - m), e2 = __expf(a2 - m), e3 = __expf(a3 - m);
    float inv = 1.f / (e0 + e1 + e2 + e3);
    float aw[4] = {e0 * inv, e1 * inv, e2 * inv, e3 * inv};

    float c = 0.f;
    #pragma unroll
    for (int hh = 0; hh < NHEADS; ++hh) {
        float l = 0.f, o = 0.f;
        #pragma unroll
        for (int s = 0; s < NSPLIT; ++s) {
            l += Lg[(s * NHEADS + hh) * N_TOK + row];
            o += bf2f(Og[(size_t)((s * NHEADS + hh) * N_TOK + row) * 64 + lane]);
        }
        c += aw[hh] * o * __builtin_amdgcn_rcpf(l);
    }

    float s = c;
    #pragma unroll
    for (int off = 32; off > 0; off >>= 1) s += __shfl_xor(s, off);
    float mu = s * (1.f / 64.f);
    float d = c - mu;
    float v = d * d;
    #pragma unroll
    for (int off = 32; off > 0; off >>= 1) v += __shfl_xor(v, off);
    float normed = d * rsqrtf(v * (1.f / 64.f) + LN_EPS) * gamma[lane] + beta[lane];

    float lg[N_CLS];
    #pragma unroll
    for (int cc = 0; cc < N_CLS; ++cc) {
        float p = normed * fc_w[lane * N_CLS + cc];
        #pragma unroll
        for (int off = 32; off > 0; off >>= 1) p += __shfl_xor(p, off);
        lg[cc] = p;
    }
    if (lane == 0) {
        #pragma unroll
        for (int cc = 0; cc < N_CLS; ++cc)
            out[row * N_CLS + cc] = lg[cc] + fc_b[cc];
    }
}

// ---------------------------------------------------------------------------
extern "C" void kernel_launch(void* const* d_in, const int* in_sizes, int n_in,
                              void* d_out, int out_size, void* d_ws, size_t ws_size,
                              hipStream_t stream)
{
    const float* x      = (const float*)d_in[0];
    const float* proj_w = (const float*)d_in[1];
    const float* proj_b = (const float*)d_in[2];
    const float* head_w = (const float*)d_in[3];
    const float* head_b = (const float*)d_in[4];
    const float* attn_w = (const float*)d_in[5];
    const float* gamma  = (const float*)d_in[6];
    const float* beta   = (const float*)d_in[7];
    const float* fc_w   = (const float*)d_in[8];
    const float* fc_b   = (const float*)d_in[9];
    float* out = (float*)d_out;

    char* ws = (char*)d_ws;
    // ws layout (bytes):
    //   hp   bf16 [4][8192][64]        @ 0          (4 MB)
    //   Vf   bf16 [4][1024][64][8]     @ 4 MB       (4 MB, key-permuted)
    //   ssq2 f32  [4][8192]            @ 8 MB       (128 KB)
    //   Og   bf16 [4][4][8192][64]     @ 8M+128K    (16 MB)
    //   Lg   f32  [4][4][8192]         @ 24M+128K   (512 KB)
    unsigned short* hp = (unsigned short*)(ws);
    unsigned short* Vf = (unsigned short*)(ws + (4u << 20));
    float* ssq2 = (float*)(ws + (8u << 20));
    unsigned short* Og = (unsigned short*)(ws + (8u << 20) + (128u << 10));
    float* Lg   = (float*)(ws + (24u << 20) + (128u << 10));

    stage1_kernel<<<N_TOK / 32, 512, 0, stream>>>(x, proj_w, proj_b, head_w, head_b,
                                                  hp, Vf, ssq2);
    dim3 g2(NHEADS * NSPLIT, N_TOK / 128);  // 16 x 64 = 1024 = 4 blocks/CU exact
    flash_kernel<<<g2, 256, 0, stream>>>(hp, Vf, ssq2, Og, Lg);
    combine_kernel<<<N_TOK / 4, 256, 0, stream>>>(Og, Lg, attn_w, gamma, beta,
                                                  fc_w, fc_b, out);
}

// Round 11
// 205.412 us; speedup vs baseline: 2.0399x; 1.0493x over previous
//
#include <hip/hip_runtime.h>

#define N_TOK 8192
#define D_IN 384
#define D_H 64
#define NHEADS 4
#define NSPLIT 4
#define N_CLS 6
#define LN_EPS 1e-5f

typedef __attribute__((ext_vector_type(8))) short short8;
typedef __attribute__((ext_vector_type(4))) float f32x4;

#define L2E2 2.08136898100560774f   /* (log2 e)^2 */

__device__ __forceinline__ unsigned short f2bf(float f) {
    unsigned int u = __float_as_uint(f);
    u += 0x7FFFu + ((u >> 16) & 1u);          // RNE (finite values only here)
    return (unsigned short)(u >> 16);
}
__device__ __forceinline__ float bf2f(unsigned short s) {
    return __uint_as_float(((unsigned int)s) << 16);
}

// Permuted key position within a 64-key tile (pairs bf16 cols for packed LDS
// writes in flash). P-columns and V-rows share the bijection -> PV invariant.
__device__ __forceinline__ int kperm(int k) {
    return (k & 32) + 2 * (k & 15) + ((k >> 4) & 1);
}

// Direct global->LDS 16B copy. LDS dest must be wave-uniform base + lane*16
// (ours is: tid*16 => wave base + lane*16). Global source is per-lane, so
// swizzled LDS layouts are made by pre-swizzling the SOURCE (rule 21).
__device__ __forceinline__ void gload_lds16(const void* g, void* l) {
    __builtin_amdgcn_global_load_lds(
        (const __attribute__((address_space(1))) unsigned int*)g,
        (__attribute__((address_space(3))) unsigned int*)l, 16, 0, 0);
}

// ---------------------------------------------------------------------------
// Fused stage 1, r24: x STAGED IN LDS. r9's structure had phase 1 issue 384
// wave-uniform 16B VMEM loads per wave for x (all lanes same address — worst
// bytes/instr, full latency chains, only 2 waves/SIMD TLP, 8 waves/block
// redundantly streaming the same 48KB). Now: 6 coalesced gload_lds16 per
// thread stage the block's 48KB of x once; phase 1 reads x as uniform LDS
// broadcasts (conflict-free, 2-cyc issue). w-loads unchanged (coalesced,
// L2-resident). LDS peak 48K x + 8.7K h + 16K vt = 72.7KB @ 1 blk/CU.
// NO cooperative / fence / finisher variants: r10 (grid.sync) and r12
// (per-block threadfence) both flushed L2 device-wide and lost 2-3x.
// ---------------------------------------------------------------------------
__global__ __launch_bounds__(512) void stage1_kernel(
    const float* __restrict__ x, const float* __restrict__ proj_w,
    const float* __restrict__ proj_b, const float* __restrict__ head_w,
    const float* __restrict__ head_b,
    unsigned short* __restrict__ hp, unsigned short* __restrict__ Vf,
    float* __restrict__ ssq2)
{
    const int lane = threadIdx.x & 63;
    const int wv   = threadIdx.x >> 6;       // 0..7
    const int rb0  = blockIdx.x * 32;
    const int tid  = threadIdx.x;

    __shared__ float x_sh[32][384];                         // 48 KB staged x
    __shared__ float h_sh[32][68];                          // [row][feat]
    __shared__ __align__(16) unsigned short vt[NHEADS][4][64][8];

    // ---- stage x rows: 48KB coalesced, 6 x 16B per thread ----
    {
        const char* xg = (const char*)(x + (size_t)rb0 * D_IN);
        #pragma unroll
        for (int i = 0; i < 6; ++i)
            gload_lds16(xg + (tid + i * 512) * 16,
                        (char*)&x_sh[0][0] + (tid + i * 512) * 16);
    }
    __syncthreads();

    // ---- phase 1: h = relu(x @ proj_w + b), 4 rows per wave ----
    {
        float acc[4];
        float b = proj_b[lane];
        #pragma unroll
        for (int r = 0; r < 4; ++r) acc[r] = b;
        const float* x0 = &x_sh[wv * 4][0];
        #pragma unroll 2
        for (int k4 = 0; k4 < D_IN / 4; ++k4) {
            float w0 = proj_w[(k4 * 4 + 0) * 64 + lane];
            float w1 = proj_w[(k4 * 4 + 1) * 64 + lane];
            float w2 = proj_w[(k4 * 4 + 2) * 64 + lane];
            float w3 = proj_w[(k4 * 4 + 3) * 64 + lane];
            #pragma unroll
            for (int r = 0; r < 4; ++r) {
                float4 xv = *(const float4*)(x0 + r * 384 + k4 * 4); // LDS broadcast
                acc[r] = fmaf(xv.x, w0, acc[r]);
                acc[r] = fmaf(xv.y, w1, acc[r]);
                acc[r] = fmaf(xv.z, w2, acc[r]);
                acc[r] = fmaf(xv.w, w3, acc[r]);
            }
        }
        #pragma unroll
        for (int r = 0; r < 4; ++r)
            h_sh[wv * 4 + r][lane] = fmaxf(acc[r], 0.f);
    }
    __syncthreads();

    // ---- phase 2: hp = h @ head_w[head] + head_b[head]; 16 rows per wave ----
    const int head = wv >> 1;
    const int half = wv & 1;
    float a[16];
    {
        float b = head_b[head * 64 + lane];
        #pragma unroll
        for (int r = 0; r < 16; ++r) a[r] = b;
    }
    const float* wb = head_w + head * 64 * 64;
    #pragma unroll 2
    for (int e4 = 0; e4 < 16; ++e4) {
        float w0 = wb[(e4 * 4 + 0) * 64 + lane];
        float w1 = wb[(e4 * 4 + 1) * 64 + lane];
        float w2 = wb[(e4 * 4 + 2) * 64 + lane];
        float w3 = wb[(e4 * 4 + 3) * 64 + lane];
        #pragma unroll
        for (int r = 0; r < 16; ++r) {
            float4 hv = *(const float4*)&h_sh[half * 16 + r][e4 * 4]; // uniform b128
            a[r] = fmaf(hv.x, w0, a[r]);
            a[r] = fmaf(hv.y, w1, a[r]);
            a[r] = fmaf(hv.z, w2, a[r]);
            a[r] = fmaf(hv.w, w3, a[r]);
        }
    }

    #pragma unroll
    for (int r = 0; r < 16; ++r) {
        int kl  = half * 16 + r;
        int row = rb0 + kl;
        unsigned short hb = f2bf(a[r]);
        float hf = bf2f(hb);
        hp[((size_t)head * N_TOK + row) * 64 + lane] = hb;
        int p = kperm(row & 63);              // halves write disjoint even/odd
        vt[head][(p >> 3) & 3][lane][p & 7] = hb;
        float s = hf * hf;
        #pragma unroll
        for (int off = 32; off > 0; off >>= 1) s += __shfl_xor(s, off);
        if (lane == 0) ssq2[head * N_TOK + row] = s * L2E2;
    }
    __syncthreads();

    // ---- write Vf coalesced: 1024 chunks of 16B, 2 per thread ----
    const int kgbase = (rb0 & 32) ? 4 : 0;
    #pragma unroll
    for (int i = 0; i < 2; ++i) {
        int c  = threadIdx.x + 512 * i;
        int hc = c >> 8, rem = c & 255;
        int kg = rem >> 6, d = rem & 63;
        short8 v = *(const short8*)&vt[hc][kg][d][0];
        *(short8*)&Vf[(((size_t)hc * (N_TOK / 8) + (rb0 >> 6) * 8 + kgbase + kg) * 64
                       + d) * 8] = v;
    }
}

// ---------------------------------------------------------------------------
// Flash distance-attention, r23 EXACT (104.4us proven; untouched this round).
// Journal:
//  r14: 16-row waves REGRESSED 1.84x (never shrink per-wave tile).
//  r15/r16: global-load reorders neutral/worse (L2 window thrash).
//  r17 (127us): LDS staging 50KB dbuf, 1 barrier, 3 blk/CU.
//  r18 (116us): 32KB single-buf, 2 barriers/tile, 4 blk/CU, 0 conflicts.
//  r19 (127us): 1-barrier dbuf at 48KB (arith error) -> 3/CU + grid tail.
//  r20 (308us): s-major spilled (CSE across s); r21 fence 120us. Abandoned.
//  r22 (114.6us): K dbuf, V+K(t+1) staged at tile top, END = pure-LDS.
//  r23 (104.4us): fabs-fold into v_sqrt (-32 v_max/tile) + setprio around
//       MFMA bursts. VALU 61% + MFMA 32% = 93% issue; trans pipe (537M
//       sqrt/exp2 wave-ops) is the floor ~85-95us. Occupancy HARD-CAPPED
//       at 4 waves/SIMD for this register class. Flash is near its limit.
// Max logit 0 (diagonal) -> no online rescaling. p = exp2(-sqrt(sq'));
// P packed bf16 pairs (kperm); O bf16. LDS 16K Psh + 16K Kdbuf + 8K V =
// 40960 = 4 blk/CU exact. Grid 16x64=1024; one head per XCD (combo&7).
// ---------------------------------------------------------------------------
__global__ __launch_bounds__(256, 4) void flash_kernel(
    const unsigned short* __restrict__ hp, const unsigned short* __restrict__ Vf,
    const float* __restrict__ ssq2, unsigned short* __restrict__ Og,
    float* __restrict__ Lg)
{
    const int head  = blockIdx.x & 3;        // combo = split*NHEADS+head
    const int split = blockIdx.x >> 2;       // 0..3
    const int q0    = blockIdx.y * 128;
    const int w     = threadIdx.x >> 6;
    const int lane  = threadIdx.x & 63;
    const int col   = lane & 15;
    const int quad  = lane >> 4;
    const int tid   = threadIdx.x;

    __shared__ __align__(16) unsigned short Psh[4][2][16][64]; // XOR-swizzled
    __shared__ __align__(16) unsigned short Kst[2][4096];      // K dbuf, swizzled
    __shared__ __align__(16) unsigned short Vst[4096];         // V single, linear

    const unsigned short* hpH = hp + head * (N_TOK * 64);
    const unsigned short* VfH = Vf + head * (N_TOK * 64);
    const float* ssqH = ssq2 + head * N_TOK;

    const int rb = q0 + w * 32;              // this wave's 32 q-rows
    const bool diag_lo = ((rb >> 5) & 1) == 0;  // both s-tiles hit d0 (else d1)

    short8 aQ[2][2];
    float ssqn2[2][4];
    #pragma unroll
    for (int s = 0; s < 2; ++s) {
        const unsigned short* qrow = hpH + (rb + s * 16 + col) * 64;
        aQ[s][0] = *(const short8*)(qrow + quad * 8);
        aQ[s][1] = *(const short8*)(qrow + 32 + quad * 8);
        #pragma unroll
        for (int r = 0; r < 4; ++r)
            ssqn2[s][r] = ssqH[rb + s * 16 + quad * 4 + r];
    }

    const f32x4 zero4 = {0.f, 0.f, 0.f, 0.f};
    f32x4 accO[2][4] = {{zero4, zero4, zero4, zero4}, {zero4, zero4, zero4, zero4}};
    f32x4 accL[2] = {zero4, zero4};
    const short8 ones = {16256,16256,16256,16256,16256,16256,16256,16256}; // bf16 1.0
    const float NEG2L2 = -2.0f * L2E2;

    // Staging: LDS chunk c linear; global source chunk = swz(c) (involution).
    const int koff0 = (((tid & ~7) | ((tid & 7) ^ ((tid >> 3) & 7))) << 4);
    // K/P read base (swizzled): row=col, chunk quad -> quad^(col&7). ^64 = +4 chunks.
    const int karow = col * 128 + ((quad ^ (col & 7)) << 4);
    const int va    = (quad * 64 + col) << 4;                  // V chunk base
    // Psh write base: row=quad*4+r, chunk (col>>2)^(row&7); +r*128 and ^(r<<4).
    const int wcb   = quad * 512 + ((((col >> 2) ^ ((quad & 1) << 2)) << 4))
                      + ((col & 3) << 2);

    const int kt0   = split * 32;
    const int ktend = kt0 + 32;

    // ---- prologue: stage K(kt0) -> Kst[0]; latency exposed once ----
    {
        const char* kg = (const char*)(hpH + kt0 * 4096);
        gload_lds16(kg + koff0,        (char*)&Kst[0][0] + tid * 16);
        gload_lds16(kg + koff0 + 4096, (char*)&Kst[0][0] + tid * 16 + 4096);
    }
    float smc[4];
    #pragma unroll
    for (int nt = 0; nt < 4; ++nt) smc[nt] = ssqH[kt0 * 64 + nt * 16 + col];
    __syncthreads();

    #pragma unroll 1
    for (int kt = kt0; kt < ktend; ++kt) {
        const int p = (kt - kt0) & 1;
        const char* Kb = (const char*)&Kst[p][0];
        const bool has_next = (kt + 1 < ktend);

        // ---- tile top: issue V(kt) AND K(kt+1); both drain at MID under
        //      the full QK+softmax cover (L2-resident, ~200-400 cyc). ----
        {
            const char* vg = (const char*)(VfH + kt * 4096);
            gload_lds16(vg + tid * 16,        (char*)Vst + tid * 16);
            gload_lds16(vg + tid * 16 + 4096, (char*)Vst + tid * 16 + 4096);
        }
        float smn[4];
        if (has_next) {
            const char* kgn = (const char*)(hpH + (kt + 1) * 4096);
            char* Kn = (char*)&Kst[p ^ 1][0];
            gload_lds16(kgn + koff0,        Kn + tid * 16);
            gload_lds16(kgn + koff0 + 4096, Kn + tid * 16 + 4096);
            #pragma unroll
            for (int nt = 0; nt < 4; ++nt)
                smn[nt] = ssqH[(kt + 1) * 64 + nt * 16 + col];
        }

        // ---- half A: S for keys 0..31 (K frags from LDS) ----
        f32x4 aSA[2][2] = {{zero4, zero4}, {zero4, zero4}};
        {
            short8 k0 = *(const short8*)(Kb + karow);
            short8 k1 = *(const short8*)(Kb + (karow ^ 64));
            short8 k2 = *(const short8*)(Kb + 2048 + karow);
            short8 k3 = *(const short8*)(Kb + 2048 + (karow ^ 64));
            __builtin_amdgcn_s_setprio(1);
            aSA[0][0] = __builtin_amdgcn_mfma_f32_16x16x32_bf16(aQ[0][0], k0, aSA[0][0], 0, 0, 0);
            aSA[0][0] = __builtin_amdgcn_mfma_f32_16x16x32_bf16(aQ[0][1], k1, aSA[0][0], 0, 0, 0);
            aSA[1][0] = __builtin_amdgcn_mfma_f32_16x16x32_bf16(aQ[1][0], k0, aSA[1][0], 0, 0, 0);
            aSA[1][0] = __builtin_amdgcn_mfma_f32_16x16x32_bf16(aQ[1][1], k1, aSA[1][0], 0, 0, 0);
            aSA[0][1] = __builtin_amdgcn_mfma_f32_16x16x32_bf16(aQ[0][0], k2, aSA[0][1], 0, 0, 0);
            aSA[0][1] = __builtin_amdgcn_mfma_f32_16x16x32_bf16(aQ[0][1], k3, aSA[0][1], 0, 0, 0);
            aSA[1][1] = __builtin_amdgcn_mfma_f32_16x16x32_bf16(aQ[1][0], k2, aSA[1][1], 0, 0, 0);
            aSA[1][1] = __builtin_amdgcn_mfma_f32_16x16x32_bf16(aQ[1][1], k3, aSA[1][1], 0, 0, 0);
            __builtin_amdgcn_s_setprio(0);
        }

        // softmax A -> d0 (swizzled chunk writes); aSA dies here
        #pragma unroll
        for (int s = 0; s < 2; ++s) {
            char* pB = (char*)&Psh[w][s][0][0];
            float pf0[4], pf1[4];
            #pragma unroll
            for (int r = 0; r < 4; ++r) {
                float sq0 = fmaf(aSA[s][0][r], NEG2L2, ssqn2[s][r] + smc[0]);
                pf0[r] = __builtin_amdgcn_exp2f(-__builtin_amdgcn_sqrtf(__builtin_fabsf(sq0)));
                float sq1 = fmaf(aSA[s][1][r], NEG2L2, ssqn2[s][r] + smc[1]);
                pf1[r] = __builtin_amdgcn_exp2f(-__builtin_amdgcn_sqrtf(__builtin_fabsf(sq1)));
            }
            #pragma unroll
            for (int r = 0; r < 4; ++r) {
                unsigned int d0 = __builtin_amdgcn_perm(__float_as_uint(pf1[r]),
                                                        __float_as_uint(pf0[r]), 0x07060302u);
                *(unsigned int*)(pB + ((wcb ^ (r << 4)) + r * 128)) = d0;
            }
        }
        // diag tile, lo half
        if (diag_lo && kt == (rb >> 6) && lane < 16) {
            #pragma unroll
            for (int s = 0; s < 2; ++s) {
                int t = ((rb + s * 16) >> 4) & 3;      // 0 or 1
                int sc2 = 4 * lane + 2 * (t & 1);
                int ad = lane * 128 + (((lane >> 2) ^ (lane & 7)) << 4) + (sc2 & 15);
                *(unsigned short*)((char*)&Psh[w][s][0][0] + ad) = 0x3F80;
            }
        }

        // ---- half B: S for keys 32..63 ----
        f32x4 aSB[2][2] = {{zero4, zero4}, {zero4, zero4}};
        {
            short8 k0 = *(const short8*)(Kb + 4096 + karow);
            short8 k1 = *(const short8*)(Kb + 4096 + (karow ^ 64));
            short8 k2 = *(const short8*)(Kb + 6144 + karow);
            short8 k3 = *(const short8*)(Kb + 6144 + (karow ^ 64));
            __builtin_amdgcn_s_setprio(1);
            aSB[0][0] = __builtin_amdgcn_mfma_f32_16x16x32_bf16(aQ[0][0], k0, aSB[0][0], 0, 0, 0);
            aSB[0][0] = __builtin_amdgcn_mfma_f32_16x16x32_bf16(aQ[0][1], k1, aSB[0][0], 0, 0, 0);
            aSB[1][0] = __builtin_amdgcn_mfma_f32_16x16x32_bf16(aQ[1][0], k0, aSB[1][0], 0, 0, 0);
            aSB[1][0] = __builtin_amdgcn_mfma_f32_16x16x32_bf16(aQ[1][1], k1, aSB[1][0], 0, 0, 0);
            aSB[0][1] = __builtin_amdgcn_mfma_f32_16x16x32_bf16(aQ[0][0], k2, aSB[0][1], 0, 0, 0);
            aSB[0][1] = __builtin_amdgcn_mfma_f32_16x16x32_bf16(aQ[0][1], k3, aSB[0][1], 0, 0, 0);
            aSB[1][1] = __builtin_amdgcn_mfma_f32_16x16x32_bf16(aQ[1][0], k2, aSB[1][1], 0, 0, 0);
            aSB[1][1] = __builtin_amdgcn_mfma_f32_16x16x32_bf16(aQ[1][1], k3, aSB[1][1], 0, 0, 0);
            __builtin_amdgcn_s_setprio(0);
        }

        // softmax B -> d1 (same swizzled addr ^ 64); aSB dies here
        #pragma unroll
        for (int s = 0; s < 2; ++s) {
            char* pB = (char*)&Psh[w][s][0][0];
            float pf2[4], pf3[4];
            #pragma unroll
            for (int r = 0; r < 4; ++r) {
                float sq2 = fmaf(aSB[s][0][r], NEG2L2, ssqn2[s][r] + smc[2]);
                pf2[r] = __builtin_amdgcn_exp2f(-__builtin_amdgcn_sqrtf(__builtin_fabsf(sq2)));
                float sq3 = fmaf(aSB[s][1][r], NEG2L2, ssqn2[s][r] + smc[3]);
                pf3[r] = __builtin_amdgcn_exp2f(-__builtin_amdgcn_sqrtf(__builtin_fabsf(sq3)));
            }
            #pragma unroll
            for (int r = 0; r < 4; ++r) {
                unsigned int d1 = __builtin_amdgcn_perm(__float_as_uint(pf3[r]),
                                                        __float_as_uint(pf2[r]), 0x07060302u);
                *(unsigned int*)(pB + (((wcb ^ (r << 4)) + r * 128) ^ 64)) = d1;
            }
        }
        // diag tile, hi half
        if (!diag_lo && kt == (rb >> 6) && lane < 16) {
            #pragma unroll
            for (int s = 0; s < 2; ++s) {
                int t = ((rb + s * 16) >> 4) & 3;      // 2 or 3
                int sc2 = 4 * lane + 2 * (t & 1);
                int ad = (lane * 128 + (((lane >> 2) ^ (lane & 7)) << 4) + (sc2 & 15)) ^ 64;
                *(unsigned short*)((char*)&Psh[w][s][0][0] + ad) = 0x3F80;
            }
        }

        // ---- MID barrier: V(kt) + K(kt+1) landed; all K(kt) reads done ----
        __syncthreads();

        // ---- PV c=0 ----
        {
            const char* p0 = (const char*)&Psh[w][0][0][0];
            const char* p1 = (const char*)&Psh[w][1][0][0];
            const char* Vb = (const char*)Vst;
            short8 aP0 = *(const short8*)(p0 + karow);
            short8 aP1 = *(const short8*)(p1 + karow);
            short8 bV[4];
            #pragma unroll
            for (int dt = 0; dt < 4; ++dt)
                bV[dt] = *(const short8*)(Vb + va + dt * 256);
            __builtin_amdgcn_s_setprio(1);
            accL[0] = __builtin_amdgcn_mfma_f32_16x16x32_bf16(aP0, ones, accL[0], 0, 0, 0);
            accL[1] = __builtin_amdgcn_mfma_f32_16x16x32_bf16(aP1, ones, accL[1], 0, 0, 0);
            #pragma unroll
            for (int dt = 0; dt < 4; ++dt) {
                accO[0][dt] = __builtin_amdgcn_mfma_f32_16x16x32_bf16(aP0, bV[dt], accO[0][dt], 0, 0, 0);
                accO[1][dt] = __builtin_amdgcn_mfma_f32_16x16x32_bf16(aP1, bV[dt], accO[1][dt], 0, 0, 0);
            }
            __builtin_amdgcn_s_setprio(0);
            // ---- PV c=1 ----
            short8 aP0b = *(const short8*)(p0 + (karow ^ 64));
            short8 aP1b = *(const short8*)(p1 + (karow ^ 64));
            #pragma unroll
            for (int dt = 0; dt < 4; ++dt)
                bV[dt] = *(const short8*)(Vb + va + dt * 256 + 4096);
            __builtin_amdgcn_s_setprio(1);
            accL[0] = __builtin_amdgcn_mfma_f32_16x16x32_bf16(aP0b, ones, accL[0], 0, 0, 0);
            accL[1] = __builtin_amdgcn_mfma_f32_16x16x32_bf16(aP1b, ones, accL[1], 0, 0, 0);
            #pragma unroll
            for (int dt = 0; dt < 4; ++dt) {
                accO[0][dt] = __builtin_amdgcn_mfma_f32_16x16x32_bf16(aP0b, bV[dt], accO[0][dt], 0, 0, 0);
                accO[1][dt] = __builtin_amdgcn_mfma_f32_16x16x32_bf16(aP1b, bV[dt], accO[1][dt], 0, 0, 0);
            }
            __builtin_amdgcn_s_setprio(0);
        }

        // ---- END barrier: pure-LDS sync (no outstanding vmem here);
        //      frees Vst + Psh for next tile top ----
        __syncthreads();
        if (has_next) {
            smc[0] = smn[0]; smc[1] = smn[1]; smc[2] = smn[2]; smc[3] = smn[3];
        }
    }

    // ---- epilogue: unnormalized O (bf16) and l (f32) for this split ----
    unsigned short* og = Og + (size_t)(split * NHEADS + head) * N_TOK * 64;
    float* lg = Lg + (size_t)(split * NHEADS + head) * N_TOK;
    #pragma unroll
    for (int s = 0; s < 2; ++s)
        #pragma unroll
        for (int r = 0; r < 4; ++r) {
            int row = rb + s * 16 + quad * 4 + r;
            #pragma unroll
            for (int dt = 0; dt < 4; ++dt)
                og[row * 64 + dt * 16 + col] = f2bf(accO[s][dt][r]);
            if (col == 0) lg[row] = accL[s][r];
        }
}

// ---------------------------------------------------------------------------
// Combine: merge NSPLIT splits, head-softmax mix, layernorm, FC. Wave per row.
// ---------------------------------------------------------------------------
__global__ __launch_bounds__(256) void combine_kernel(
    const unsigned short* __restrict__ Og, const float* __restrict__ Lg,
    const float* __restrict__ attn_w, const float* __restrict__ gamma,
    const float* __restrict__ beta, const float* __restrict__ fc_w,
    const float* __restrict__ fc_b, float* __restrict__ out)
{
    const int lane = threadIdx.x & 63;
    const int ty   = threadIdx.x >> 6;
    const int row  = blockIdx.x * 4 + ty;

    float a0 = attn_w[0], a1 = attn_w[1], a2 = attn_w[2], a3 = attn_w[3];
    float m = fmaxf(fmaxf(a0, a1), fmaxf(a2, a3));
    float e0 = __expf(a0 - m), e1 = __expf(a1 - m), e2 = __expf(a2 - m), e3 = __expf(a3 - m);
    float inv = 1.f / (e0 + e1 + e2 + e3);
    float aw[4] = {e0 * inv, e1 * inv, e2 * inv, e3 * inv};

    float c = 0.f;
    #pragma unroll
    for (int hh = 0; hh < NHEADS; ++hh) {
        float l = 0.f, o = 0.f;
        #pragma unroll
        for (int s = 0; s < NSPLIT; ++s) {
            l += Lg[(s * NHEADS + hh) * N_TOK + row];
            o += bf2f(Og[(size_t)((s * NHEADS + hh) * N_TOK + row) * 64 + lane]);
        }
        c += aw[hh] * o * __builtin_amdgcn_rcpf(l);
    }

    float s = c;
    #pragma unroll
    for (int off = 32; off > 0; off >>= 1) s += __shfl_xor(s, off);
    float mu = s * (1.f / 64.f);
    float d = c - mu;
    float v = d * d;
    #pragma unroll
    for (int off = 32; off > 0; off >>= 1) v += __shfl_xor(v, off);
    float normed = d * rsqrtf(v * (1.f / 64.f) + LN_EPS) * gamma[lane] + beta[lane];

    float lg[N_CLS];
    #pragma unroll
    for (int cc = 0; cc < N_CLS; ++cc) {
        float p = normed * fc_w[lane * N_CLS + cc];
        #pragma unroll
        for (int off = 32; off > 0; off >>= 1) p += __shfl_xor(p, off);
        lg[cc] = p;
    }
    if (lane == 0) {
        #pragma unroll
        for (int cc = 0; cc < N_CLS; ++cc)
            out[row * N_CLS + cc] = lg[cc] + fc_b[cc];
    }
}

// ---------------------------------------------------------------------------
extern "C" void kernel_launch(void* const* d_in, const int* in_sizes, int n_in,
                              void* d_out, int out_size, void* d_ws, size_t ws_size,
                              hipStream_t stream)
{
    const float* x      = (const float*)d_in[0];
    const float* proj_w = (const float*)d_in[1];
    const float* proj_b = (const float*)d_in[2];
    const float* head_w = (const float*)d_in[3];
    const float* head_b = (const float*)d_in[4];
    const float* attn_w = (const float*)d_in[5];
    const float* gamma  = (const float*)d_in[6];
    const float* beta   = (const float*)d_in[7];
    const float* fc_w   = (const float*)d_in[8];
    const float* fc_b   = (const float*)d_in[9];
    float* out = (float*)d_out;

    char* ws = (char*)d_ws;
    // ws layout (bytes):
    //   hp   bf16 [4][8192][64]        @ 0          (4 MB)
    //   Vf   bf16 [4][1024][64][8]     @ 4 MB       (4 MB, key-permuted)
    //   ssq2 f32  [4][8192]            @ 8 MB       (128 KB)
    //   Og   bf16 [4][4][8192][64]     @ 8M+128K    (16 MB)
    //   Lg   f32  [4][4][8192]         @ 24M+128K   (512 KB)
    unsigned short* hp = (unsigned short*)(ws);
    unsigned short* Vf = (unsigned short*)(ws + (4u << 20));
    float* ssq2 = (float*)(ws + (8u << 20));
    unsigned short* Og = (unsigned short*)(ws + (8u << 20) + (128u << 10));
    float* Lg   = (float*)(ws + (24u << 20) + (128u << 10));

    stage1_kernel<<<N_TOK / 32, 512, 0, stream>>>(x, proj_w, proj_b, head_w, head_b,
                                                  hp, Vf, ssq2);
    dim3 g2(NHEADS * NSPLIT, N_TOK / 128);  // 16 x 64 = 1024 = 4 blocks/CU exact
    flash_kernel<<<g2, 256, 0, stream>>>(hp, Vf, ssq2, Og, Lg);
    combine_kernel<<<N_TOK / 4, 256, 0, stream>>>(Og, Lg, attn_w, gamma, beta,
                                                  fc_w, fc_b, out);
}